// Round 8
// baseline (1425.433 us; speedup 1.0000x reference)
//
#include <hip/hip_runtime.h>

#define NU 100000
#define NM 20000
#define NE 2000000
#define NL 500000
#define H  128

typedef __attribute__((ext_vector_type(8))) short bf16x8;            // 8 bf16 (4 VGPRs)
typedef __attribute__((ext_vector_type(4))) float floatx4;           // 4 fp32 acc
typedef __attribute__((ext_vector_type(8))) unsigned short u16x8;    // 16B load/store
typedef __attribute__((ext_vector_type(4))) unsigned short u16x4;    // 8B store

__device__ __forceinline__ unsigned short f2b(float x) {
    union { float f; unsigned u; } v; v.f = x;
    unsigned r = v.u + 0x7FFFu + ((v.u >> 16) & 1u);  // RNE
    return (unsigned short)(r >> 16);
}
__device__ __forceinline__ float b2f(unsigned short h) {
    union { unsigned u; float f; } v; v.u = ((unsigned)h) << 16;
    return v.f;
}
__device__ __forceinline__ float b2f_lo(unsigned v) {  // low ushort of packed pair
    union { unsigned u; float f; } t; t.u = v << 16; return t.f;
}
__device__ __forceinline__ float b2f_hi(unsigned v) {
    union { unsigned u; float f; } t; t.u = v & 0xFFFF0000u; return t.f;
}

// rotated LDS chunk addressing (chunk = 16B = 8 bf16), zero-waste bank pad.
#define SFCH(r, c)  ((r) * 32 + (((c) + (r)) & 31))   // 64 rows x 32 chunks (256 cols)
#define SH1CH(r, c) ((r) * 16 + (((c) + (r)) & 15))   // 64 rows x 16 chunks (128 cols)

// ---------------------------------------------------------------- transpose (proj weights only)
struct TDesc { const float* s; float* d; int R; int C; };
struct TPack { TDesc t[2]; };

__global__ __launch_bounds__(256) void transpose_all(TPack p) {
    TDesc d = p.t[blockIdx.y];
    int n = d.R * d.C;
    for (int i = blockIdx.x * 256 + threadIdx.x; i < n; i += gridDim.x * 256) {
        int r = i / d.C, c = i - r * d.C;
        d.d[c * d.R + r] = d.s[i];  // dst[k][h] = src[h][k]
    }
}

// ---------------------------------------------------------------- pack decoder weights into MFMA B-frag order
__global__ __launch_bounds__(256) void pack_weights(const float* __restrict__ W1,
                                                    const float* __restrict__ W2,
                                                    unsigned short* __restrict__ W1p,
                                                    unsigned short* __restrict__ W2p) {
    const int n = 512 * 256;
    for (int i = blockIdx.x * 256 + threadIdx.x; i < n; i += gridDim.x * 256) {
        int j = i & 7, lane = (i >> 3) & 63;
        int ln = lane & 15, lq = lane >> 4;
        int kg1 = (i >> 9) & 7,  t1 = i >> 12;
        W1p[i] = f2b(W1[(t1 * 16 + ln) * 256 + kg1 * 32 + lq * 8 + j]);
        int kg2 = (i >> 9) & 15, t2 = i >> 13;
        W2p[i] = f2b(W2[(t2 * 16 + ln) * 512 + kg2 * 32 + lq * 8 + j]);
    }
}

// ---------------------------------------------------------------- pack 8 sage weights (H x H) into B-frag order
struct SPack { const float* w[8]; };
__global__ __launch_bounds__(256) void pack_sage(SPack sp, unsigned short* __restrict__ out) {
    const int n = 8 * 16384;
    for (int i = blockIdx.x * 256 + threadIdx.x; i < n; i += gridDim.x * 256) {
        int j = i & 7, lane = (i >> 3) & 63;
        int kg = (i >> 9) & 3, t = (i >> 11) & 7, wsel = i >> 14;
        int ln = lane & 15, lq = lane >> 4;
        out[i] = f2b(sp.w[wsel][(t * 16 + ln) * H + kg * 32 + lq * 8 + j]);
    }
}

// ---------------------------------------------------------------- CSR build
__global__ __launch_bounds__(256) void deg_kernel(const int* __restrict__ ei,
                                                  int* rp_m, int* rp_u) {
    for (int i = blockIdx.x * 256 + threadIdx.x; i < NE; i += gridDim.x * 256) {
        int u = ei[i], m = ei[NE + i];
        atomicAdd(&rp_u[u + 1], 1);
        atomicAdd(&rp_m[m + 1], 1);
    }
}

__global__ __launch_bounds__(256) void scan2_kernel(int* rp_m, int n_m,
                                                    int* rp_u, int n_u) {
    int* a = (blockIdx.x == 0) ? rp_m : rp_u;
    int n  = (blockIdx.x == 0) ? n_m : n_u;
    __shared__ int s[256];
    __shared__ int carry;
    int tid = threadIdx.x;
    if (tid == 0) carry = 0;
    __syncthreads();
    for (int base = 0; base < n; base += 4096) {
        int v[16];
        int run = 0;
        int i0 = base + tid * 16;
#pragma unroll
        for (int i = 0; i < 16; ++i) {
            int x = (i0 + i < n) ? a[i0 + i] : 0;
            run += x; v[i] = run;
        }
        s[tid] = run;
        __syncthreads();
        for (int off = 1; off < 256; off <<= 1) {
            int t = (tid >= off) ? s[tid - off] : 0;
            __syncthreads();
            s[tid] += t;
            __syncthreads();
        }
        int prev = carry + (tid > 0 ? s[tid - 1] : 0);
#pragma unroll
        for (int i = 0; i < 16; ++i)
            if (i0 + i < n) a[i0 + i] = v[i] + prev;
        int total = s[255];
        __syncthreads();
        if (tid == 0) carry += total;
        __syncthreads();
    }
}

__global__ __launch_bounds__(256) void bucket_kernel(const int* __restrict__ ei,
        const int* __restrict__ rp_m, const int* __restrict__ rp_u,
        int* cur_m, int* cur_u, int* es_m, int* es_u) {
    for (int i = blockIdx.x * 256 + threadIdx.x; i < NE; i += gridDim.x * 256) {
        int u = ei[i], m = ei[NE + i];
        int pm = atomicAdd(&cur_m[m], 1);
        es_m[rp_m[m] + pm] = u;
        int pu = atomicAdd(&cur_u[u], 1);
        es_u[rp_u[u] + pu] = m;
    }
}

// ---------------------------------------------------------------- projection (Linear + BN(eval) + ReLU) -> bf16
template <int K>
__global__ __launch_bounds__(256, 2) void proj_kernel(
        const float* __restrict__ x, const float* __restrict__ Wt,
        const float* __restrict__ lb, const float* __restrict__ g,
        const float* __restrict__ bb, const float* __restrict__ bm,
        const float* __restrict__ bv, unsigned short* __restrict__ out, int N) {
    __shared__ float sA[64 * K];
    const int tid = threadIdx.x;
    const int row0 = blockIdx.x * 64;
    constexpr int F4 = K / 4;
#pragma unroll
    for (int i = 0; i < (64 * F4) / 256; ++i) {
        int idx = tid + i * 256;
        int r = idx / F4, c = idx - r * F4;
        int gr = min(row0 + r, N - 1);
        ((float4*)sA)[idx] = ((const float4*)(x + (size_t)gr * K))[c];
    }
    __syncthreads();
    const int h_t = tid & 31, r_t = tid >> 5;
    float acc[8][4] = {};
#pragma unroll 4
    for (int k = 0; k < K; k += 4) {
        float4 w[4];
#pragma unroll
        for (int kk = 0; kk < 4; ++kk)
            w[kk] = *(const float4*)(Wt + (k + kk) * H + h_t * 4);
#pragma unroll
        for (int rr = 0; rr < 8; ++rr) {
            float4 a = *(const float4*)(sA + (r_t * 8 + rr) * K + k);
            acc[rr][0] += a.x * w[0].x + a.y * w[1].x + a.z * w[2].x + a.w * w[3].x;
            acc[rr][1] += a.x * w[0].y + a.y * w[1].y + a.z * w[2].y + a.w * w[3].y;
            acc[rr][2] += a.x * w[0].z + a.y * w[1].z + a.z * w[2].z + a.w * w[3].z;
            acc[rr][3] += a.x * w[0].w + a.y * w[1].w + a.z * w[2].w + a.w * w[3].w;
        }
    }
    const int h = h_t * 4;
    float4 lb4 = *(const float4*)(lb + h);
    float4 g4  = *(const float4*)(g  + h);
    float4 bb4 = *(const float4*)(bb + h);
    float4 m4  = *(const float4*)(bm + h);
    float4 v4  = *(const float4*)(bv + h);
    float sc[4] = { g4.x * rsqrtf(v4.x + 1e-5f), g4.y * rsqrtf(v4.y + 1e-5f),
                    g4.z * rsqrtf(v4.z + 1e-5f), g4.w * rsqrtf(v4.w + 1e-5f) };
    float lbv[4] = { lb4.x, lb4.y, lb4.z, lb4.w };
    float mv[4]  = { m4.x, m4.y, m4.z, m4.w };
    float bbv[4] = { bb4.x, bb4.y, bb4.z, bb4.w };
#pragma unroll
    for (int rr = 0; rr < 8; ++rr) {
        int gr = row0 + r_t * 8 + rr;
        if (gr < N) {
            u16x4 o;
#pragma unroll
            for (int c = 0; c < 4; ++c)
                o[c] = f2b(fmaxf((acc[rr][c] + lbv[c] - mv[c]) * sc[c] + bbv[c], 0.0f));
            *(u16x4*)(out + (size_t)gr * H + h) = o;
        }
    }
}

// ---------------------------------------------------------------- segment mean (bf16 in/out, fp32 acc)
// one WAVE per node; both directions fused.
__global__ __launch_bounds__(256) void agg_bf16(
        const unsigned short* __restrict__ srcA, const int* __restrict__ esA,
        const int* __restrict__ rpA, unsigned short* __restrict__ outA, int nA,
        const unsigned short* __restrict__ srcB, const int* __restrict__ esB,
        const int* __restrict__ rpB, unsigned short* __restrict__ outB, int nB) {
    int wid = blockIdx.x * 4 + (threadIdx.x >> 6);
    const int lane = threadIdx.x & 63;
    const unsigned short* src; const int* es; const int* rp; unsigned short* out; int n;
    if (wid < nA) { src = srcA; es = esA; rp = rpA; out = outA; n = wid; }
    else {
        wid -= nA;
        if (wid >= nB) return;
        src = srcB; es = esB; rp = rpB; out = outB; n = wid;
    }
    const int start = rp[n], end = rp[n + 1];
    float a0 = 0.0f, a1 = 0.0f;
    int j = start;
    for (; j + 4 <= end; j += 4) {
        int s0 = es[j], s1 = es[j + 1], s2 = es[j + 2], s3 = es[j + 3];
        unsigned v0 = *(const unsigned*)(src + (size_t)s0 * H + lane * 2);
        unsigned v1 = *(const unsigned*)(src + (size_t)s1 * H + lane * 2);
        unsigned v2 = *(const unsigned*)(src + (size_t)s2 * H + lane * 2);
        unsigned v3 = *(const unsigned*)(src + (size_t)s3 * H + lane * 2);
        a0 += b2f_lo(v0); a1 += b2f_hi(v0);
        a0 += b2f_lo(v1); a1 += b2f_hi(v1);
        a0 += b2f_lo(v2); a1 += b2f_hi(v2);
        a0 += b2f_lo(v3); a1 += b2f_hi(v3);
    }
    for (; j < end; ++j) {
        unsigned v = *(const unsigned*)(src + (size_t)es[j] * H + lane * 2);
        a0 += b2f_lo(v); a1 += b2f_hi(v);
    }
    float inv = (end > start) ? 1.0f / (float)(end - start) : 0.0f;
    unsigned o = (unsigned)f2b(a0 * inv) | ((unsigned)f2b(a1 * inv) << 16);
    *(unsigned*)(out + (size_t)n * H + lane * 2) = o;
}

// ---------------------------------------------------------------- SAGE via MFMA
__global__ __launch_bounds__(256, 4) void sage_mfma(
        const unsigned short* __restrict__ aggA, const unsigned short* __restrict__ xA,
        const unsigned short* __restrict__ WlA, const unsigned short* __restrict__ WrA,
        const float* __restrict__ blA, unsigned short* __restrict__ outA, int NA, int NBLKA,
        const unsigned short* __restrict__ aggB, const unsigned short* __restrict__ xB,
        const unsigned short* __restrict__ WlB, const unsigned short* __restrict__ WrB,
        const float* __restrict__ blB, unsigned short* __restrict__ outB, int NB,
        int relu) {
    __shared__ unsigned short sAg[64 * 16 * 8];  // 16 KB
    __shared__ unsigned short sX[64 * 16 * 8];   // 16 KB
    const int tid = threadIdx.x;
    const unsigned short *agg, *x, *Wl, *Wr; const float* bl; unsigned short* out;
    int N, row0;
    if ((int)blockIdx.x < NBLKA) {
        agg = aggA; x = xA; Wl = WlA; Wr = WrA; bl = blA; out = outA; N = NA;
        row0 = blockIdx.x * 64;
    } else {
        agg = aggB; x = xB; Wl = WlB; Wr = WrB; bl = blB; out = outB; N = NB;
        row0 = (blockIdx.x - NBLKA) * 64;
    }
#pragma unroll
    for (int i = 0; i < 4; ++i) {
        int idx = tid + i * 256;           // 1024 chunks
        int r = idx >> 4, c = idx & 15;
        int gr = min(row0 + r, N - 1);
        *(u16x8*)(sAg + SH1CH(r, c) * 8) = *(const u16x8*)(agg + (size_t)gr * H + c * 8);
        *(u16x8*)(sX  + SH1CH(r, c) * 8) = *(const u16x8*)(x   + (size_t)gr * H + c * 8);
    }
    __syncthreads();
    const int lane = tid & 63, w = tid >> 6;
    const int ln = lane & 15, lq = lane >> 4;
    floatx4 acc[2][4] = {};
#pragma unroll 2
    for (int kg = 0; kg < 4; ++kg) {
        bf16x8 aA[4], aX[4];
#pragma unroll
        for (int mt = 0; mt < 4; ++mt) {
            aA[mt] = *(const bf16x8*)(sAg + SH1CH(mt * 16 + ln, kg * 4 + lq) * 8);
            aX[mt] = *(const bf16x8*)(sX  + SH1CH(mt * 16 + ln, kg * 4 + lq) * 8);
        }
#pragma unroll
        for (int nt = 0; nt < 2; ++nt) {
            int widx = ((w * 2 + nt) * 4 + kg) * 512 + lane * 8;
            bf16x8 bL = *(const bf16x8*)(Wl + widx);
            bf16x8 bR = *(const bf16x8*)(Wr + widx);
#pragma unroll
            for (int mt = 0; mt < 4; ++mt) {
                acc[nt][mt] = __builtin_amdgcn_mfma_f32_16x16x32_bf16(aA[mt], bL, acc[nt][mt], 0, 0, 0);
                acc[nt][mt] = __builtin_amdgcn_mfma_f32_16x16x32_bf16(aX[mt], bR, acc[nt][mt], 0, 0, 0);
            }
        }
    }
    __syncthreads();   // done reading sAg; reuse it for output staging
    {
#pragma unroll
        for (int nt = 0; nt < 2; ++nt) {
            int ncol = w * 32 + nt * 16 + ln;   // 0..127
            float bv = bl[ncol];
            int cch = ncol >> 3, coff = ncol & 7;
#pragma unroll
            for (int mt = 0; mt < 4; ++mt)
#pragma unroll
                for (int i = 0; i < 4; ++i) {
                    int row = mt * 16 + lq * 4 + i;
                    float v = acc[nt][mt][i] + bv;
                    if (relu) v = fmaxf(v, 0.0f);
                    sAg[SH1CH(row, cch) * 8 + coff] = f2b(v);
                }
        }
    }
    __syncthreads();
#pragma unroll
    for (int i = 0; i < 4; ++i) {
        int idx = tid + i * 256;
        int r = idx >> 4, c = idx & 15;
        int gr = row0 + r;
        if (gr < N)
            *(u16x8*)(out + (size_t)gr * H + c * 8) = *(const u16x8*)(sAg + SH1CH(r, c) * 8);
    }
}

// ---------------------------------------------------------------- fused edge decoder MLP
// 2-pass, 8 waves, __launch_bounds__(512,2): 256 unified regs/wave.
// acc1[2][4]=32 + acc3[2][4]=32 AGPR + full-unroll arch regs fit 256 with NO
// scratch spill (R7's (512,4)=128-reg budget spilled 200 MB; 1 block/CU is
// resident either way, so the extra occupancy declaration bought nothing).
// Each A-read feeds 2 MFMAs (nt=2) -> 128 b128 LDS reads/wave (vs 192 at 4-pass).
__global__ __launch_bounds__(512, 2) void decoder_mfma(
        const unsigned short* __restrict__ zu, const unsigned short* __restrict__ zm,
        const int* __restrict__ eli,
        const unsigned short* __restrict__ W1p, const float* __restrict__ b1,
        const unsigned short* __restrict__ W2p, const float* __restrict__ b2,
        const float* __restrict__ W3, const float* __restrict__ b3,
        float* __restrict__ out) {
    __shared__ unsigned short sF[64 * 32 * 8];   // feat 64x256 bf16 rotated (32 KB), later h2
    __shared__ unsigned short sH1[64 * 32 * 8];  // h1 half 64x256 bf16 rotated (32 KB)
    const int tid = threadIdx.x;
    const int row0 = blockIdx.x * 64;
    // ---- gather feat = [zu[eu] | zm[em]] (bf16 straight copy)
    {
        int r = tid >> 3, p = tid & 7;
        int rg = min(row0 + r, NL - 1);
        int iu = eli[rg], im = eli[NL + rg];
        const unsigned short* zur = zu + (size_t)iu * H;
        const unsigned short* zmr = zm + (size_t)im * H;
#pragma unroll
        for (int j = 0; j < 4; ++j) {
            int c = p + j * 8;   // 0..31
            const unsigned short* s = (c < 16) ? (zur + c * 8) : (zmr + (c - 16) * 8);
            *(u16x8*)(sF + SFCH(r, c) * 8) = *(const u16x8*)s;
        }
    }
    __syncthreads();
    const int lane = tid & 63, w = tid >> 6;   // 8 waves
    const int ln = lane & 15, lq = lane >> 4;
    floatx4 acc3[2][4] = {};   // layer-2 accumulator, persists across both k-halves
#pragma unroll 1
    for (int h = 0; h < 2; ++h) {
        // ---- layer 1 (n-half h): wave w owns n-cols [h*256 + w*32, +32)
        floatx4 acc1[2][4] = {};
        const unsigned short* w1base = W1p + ((size_t)(h * 16 + w * 2) * 8) * 512 + lane * 8;
#pragma unroll
        for (int kg = 0; kg < 8; ++kg) {
            bf16x8 a[4];
#pragma unroll
            for (int mt = 0; mt < 4; ++mt)
                a[mt] = *(const bf16x8*)(sF + SFCH(mt * 16 + ln, kg * 4 + lq) * 8);
#pragma unroll
            for (int nt = 0; nt < 2; ++nt) {
                bf16x8 b = *(const bf16x8*)(w1base + (size_t)(nt * 8 + kg) * 512);
#pragma unroll
                for (int mt = 0; mt < 4; ++mt)
                    acc1[nt][mt] = __builtin_amdgcn_mfma_f32_16x16x32_bf16(a[mt], b, acc1[nt][mt], 0, 0, 0);
            }
        }
        {   // epilogue: +b1, ReLU, store bf16 to sH1 (rotated, A-layout)
#pragma unroll
            for (int nt = 0; nt < 2; ++nt) {
                int ncol = w * 32 + nt * 16 + ln;     // 0..255 within half
                float bv = b1[h * 256 + ncol];
                int cch = ncol >> 3, coff = ncol & 7;
#pragma unroll
                for (int mt = 0; mt < 4; ++mt)
#pragma unroll
                    for (int i = 0; i < 4; ++i) {
                        int row = mt * 16 + lq * 4 + i;
                        sH1[SFCH(row, cch) * 8 + coff] = f2b(fmaxf(acc1[nt][mt][i] + bv, 0.0f));
                    }
            }
        }
        __syncthreads();
        // ---- layer 2 partial: acc3 += h1half @ W2[k-half h]; wave w owns n-cols [w*32,+32)
        const unsigned short* w2base = W2p + ((size_t)(w * 2) * 16 + h * 8) * 512 + lane * 8;
#pragma unroll
        for (int kg = 0; kg < 8; ++kg) {
            bf16x8 a[4];
#pragma unroll
            for (int mt = 0; mt < 4; ++mt)
                a[mt] = *(const bf16x8*)(sH1 + SFCH(mt * 16 + ln, kg * 4 + lq) * 8);
#pragma unroll
            for (int nt = 0; nt < 2; ++nt) {
                bf16x8 b = *(const bf16x8*)(w2base + (size_t)(nt * 16 + kg) * 512);
#pragma unroll
                for (int mt = 0; mt < 4; ++mt)
                    acc3[nt][mt] = __builtin_amdgcn_mfma_f32_16x16x32_bf16(a[mt], b, acc3[nt][mt], 0, 0, 0);
            }
        }
        __syncthreads();   // before next half overwrites sH1
    }
    {   // ---- h2 = ReLU(acc3 + b2) -> sF overlay (feat dead), rotated
#pragma unroll
        for (int nt = 0; nt < 2; ++nt) {
            int ncol = w * 32 + nt * 16 + ln;   // 0..255
            float bv = b2[ncol];
            int cch = ncol >> 3, coff = ncol & 7;
#pragma unroll
            for (int mt = 0; mt < 4; ++mt)
#pragma unroll
                for (int i = 0; i < 4; ++i) {
                    int row = mt * 16 + lq * 4 + i;
                    sF[SFCH(row, cch) * 8 + coff] = f2b(fmaxf(acc3[nt][mt][i] + bv, 0.0f));
                }
        }
    }
    __syncthreads();
    // ---- layer 3: out = h2 @ W3^T + b3
    {
        int r = tid >> 3, p = tid & 7;   // 64 rows x 8 threads (32 cols each)
        float sum = 0.0f;
#pragma unroll
        for (int j = 0; j < 4; ++j) {
            int c = p + j * 8;
            const unsigned short* hp = sF + SFCH(r, c) * 8;
            const float* w3p = W3 + c * 8;
#pragma unroll
            for (int e = 0; e < 8; ++e) sum += b2f(hp[e]) * w3p[e];
        }
        sum += __shfl_down(sum, 4, 8);
        sum += __shfl_down(sum, 2, 8);
        sum += __shfl_down(sum, 1, 8);
        if (p == 0 && row0 + r < NL) out[row0 + r] = sum + b3[0];
    }
}

// ---------------------------------------------------------------- host
extern "C" void kernel_launch(void* const* d_in, const int* in_sizes, int n_in,
                              void* d_out, int out_size, void* d_ws, size_t ws_size,
                              hipStream_t stream) {
    const float* x_user  = (const float*)d_in[0];
    const float* x_movie = (const float*)d_in[1];
    const int*   ei      = (const int*)d_in[2];
    const int*   eli     = (const int*)d_in[3];
    const float* lin_u_W = (const float*)d_in[4];
    const float* lin_u_b = (const float*)d_in[5];
    const float* lin_m_W = (const float*)d_in[6];
    const float* lin_m_b = (const float*)d_in[7];
    const float* bn_u_g  = (const float*)d_in[8];
    const float* bn_u_b  = (const float*)d_in[9];
    const float* bn_u_m  = (const float*)d_in[10];
    const float* bn_u_v  = (const float*)d_in[11];
    const float* bn_m_g  = (const float*)d_in[12];
    const float* bn_m_b  = (const float*)d_in[13];
    const float* bn_m_m  = (const float*)d_in[14];
    const float* bn_m_v  = (const float*)d_in[15];
    const float* c1_um_Wl = (const float*)d_in[16];
    const float* c1_um_bl = (const float*)d_in[17];
    const float* c1_um_Wr = (const float*)d_in[18];
    const float* c1_mu_Wl = (const float*)d_in[19];
    const float* c1_mu_bl = (const float*)d_in[20];
    const float* c1_mu_Wr = (const float*)d_in[21];
    const float* c2_um_Wl = (const float*)d_in[22];
    const float* c2_um_bl = (const float*)d_in[23];
    const float* c2_um_Wr = (const float*)d_in[24];
    const float* c2_mu_Wl = (const float*)d_in[25];
    const float* c2_mu_bl = (const float*)d_in[26];
    const float* c2_mu_Wr = (const float*)d_in[27];
    const float* dec_W1 = (const float*)d_in[28];
    const float* dec_b1 = (const float*)d_in[29];
    const float* dec_W2 = (const float*)d_in[30];
    const float* dec_b2 = (const float*)d_in[31];
    const float* dec_W3 = (const float*)d_in[32];
    const float* dec_b3 = (const float*)d_in[33];

    char* base = (char*)d_ws;
    size_t off = 0;
    auto alloc = [&](size_t bytes) -> char* {
        char* p = base + off;
        off += (bytes + 255) & ~(size_t)255;
        return p;
    };
    unsigned short* xu_b  = (unsigned short*)alloc((size_t)NU * H * 2);
    unsigned short* xm_b  = (unsigned short*)alloc((size_t)NM * H * 2);
    unsigned short* xu1_b = (unsigned short*)alloc((size_t)NU * H * 2);
    unsigned short* xm1_b = (unsigned short*)alloc((size_t)NM * H * 2);
    unsigned short* aggu  = (unsigned short*)alloc((size_t)NU * H * 2);
    unsigned short* aggm  = (unsigned short*)alloc((size_t)NM * H * 2);
    float* wt_u = (float*)alloc((size_t)64 * H * 4);
    float* wt_m = (float*)alloc((size_t)H * H * 4);
    unsigned short* wsg = (unsigned short*)alloc((size_t)8 * 16384 * 2);  // packed sage weights
    unsigned short* w1p = (unsigned short*)alloc((size_t)512 * 256 * 2);
    unsigned short* w2p = (unsigned short*)alloc((size_t)256 * 512 * 2);
    int* rp_m  = (int*)alloc((size_t)(NM + 1) * 4);
    int* rp_u  = (int*)alloc((size_t)(NU + 1) * 4);
    int* cur_m = (int*)alloc((size_t)NM * 4);
    int* cur_u = (int*)alloc((size_t)NU * 4);
    int* es_m  = (int*)alloc((size_t)NE * 4);
    int* es_u  = (int*)alloc((size_t)NE * 4);
    unsigned short* zu = xu_b;   // xu_b dead after conv1 sage -> reuse
    unsigned short* zm = xm_b;

    // zero CSR meta (rp_m .. cur_u incl. padding)
    hipMemsetAsync(rp_m, 0, (size_t)((char*)es_m - (char*)rp_m), stream);

    TPack tp;
    tp.t[0] = { lin_u_W, wt_u, H, 64 };
    tp.t[1] = { lin_m_W, wt_m, H, H };
    transpose_all<<<dim3(64, 2), 256, 0, stream>>>(tp);
    pack_weights<<<256, 256, 0, stream>>>(dec_W1, dec_W2, w1p, w2p);
    SPack sp;
    sp.w[0] = c1_um_Wl; sp.w[1] = c1_um_Wr; sp.w[2] = c1_mu_Wl; sp.w[3] = c1_mu_Wr;
    sp.w[4] = c2_um_Wl; sp.w[5] = c2_um_Wr; sp.w[6] = c2_mu_Wl; sp.w[7] = c2_mu_Wr;
    pack_sage<<<128, 256, 0, stream>>>(sp, wsg);
    const unsigned short* W_c1um_l = wsg + 0 * 16384;
    const unsigned short* W_c1um_r = wsg + 1 * 16384;
    const unsigned short* W_c1mu_l = wsg + 2 * 16384;
    const unsigned short* W_c1mu_r = wsg + 3 * 16384;
    const unsigned short* W_c2um_l = wsg + 4 * 16384;
    const unsigned short* W_c2um_r = wsg + 5 * 16384;
    const unsigned short* W_c2mu_l = wsg + 6 * 16384;
    const unsigned short* W_c2mu_r = wsg + 7 * 16384;

    deg_kernel<<<2048, 256, 0, stream>>>(ei, rp_m, rp_u);
    scan2_kernel<<<2, 256, 0, stream>>>(rp_m, NM + 1, rp_u, NU + 1);
    bucket_kernel<<<2048, 256, 0, stream>>>(ei, rp_m, rp_u, cur_m, cur_u, es_m, es_u);

    proj_kernel<64><<<(NU + 63) / 64, 256, 0, stream>>>(
        x_user, wt_u, lin_u_b, bn_u_g, bn_u_b, bn_u_m, bn_u_v, xu_b, NU);
    proj_kernel<128><<<(NM + 63) / 64, 256, 0, stream>>>(
        x_movie, wt_m, lin_m_b, bn_m_g, bn_m_b, bn_m_m, bn_m_v, xm_b, NM);

    const int AGG_BLOCKS = (NM + NU + 3) / 4;
    const int NBLK_M = (NM + 63) / 64, NBLK_U = (NU + 63) / 64;

    // conv1
    agg_bf16<<<AGG_BLOCKS, 256, 0, stream>>>(xu_b, es_m, rp_m, aggm, NM,
                                             xm_b, es_u, rp_u, aggu, NU);
    sage_mfma<<<NBLK_M + NBLK_U, 256, 0, stream>>>(
        aggm, xm_b, W_c1um_l, W_c1um_r, c1_um_bl, xm1_b, NM, NBLK_M,
        aggu, xu_b, W_c1mu_l, W_c1mu_r, c1_mu_bl, xu1_b, NU, 1);
    // conv2
    agg_bf16<<<AGG_BLOCKS, 256, 0, stream>>>(xu1_b, es_m, rp_m, aggm, NM,
                                             xm1_b, es_u, rp_u, aggu, NU);
    sage_mfma<<<NBLK_M + NBLK_U, 256, 0, stream>>>(
        aggm, xm1_b, W_c2um_l, W_c2um_r, c2_um_bl, zm, NM, NBLK_M,
        aggu, xu1_b, W_c2mu_l, W_c2mu_r, c2_mu_bl, zu, NU, 0);

    // decoder (bf16 MFMA, 2-pass fused 3-layer MLP, 256 regs/wave)
    decoder_mfma<<<(NL + 63) / 64, 512, 0, stream>>>(
        zu, zm, eli, w1p, dec_b1, w2p, dec_b2, dec_W3, dec_b3, (float*)d_out);
}

// Round 9
// 1317.775 us; speedup vs baseline: 1.0817x; 1.0817x over previous
//
#include <hip/hip_runtime.h>

#define NU 100000
#define NM 20000
#define NE 2000000
#define NL 500000
#define H  128

typedef __attribute__((ext_vector_type(8))) short bf16x8;            // 8 bf16 (4 VGPRs)
typedef __attribute__((ext_vector_type(4))) float floatx4;           // 4 fp32 acc
typedef __attribute__((ext_vector_type(8))) unsigned short u16x8;    // 16B load/store
typedef __attribute__((ext_vector_type(4))) unsigned short u16x4;    // 8B store

__device__ __forceinline__ unsigned short f2b(float x) {
    union { float f; unsigned u; } v; v.f = x;
    unsigned r = v.u + 0x7FFFu + ((v.u >> 16) & 1u);  // RNE
    return (unsigned short)(r >> 16);
}
__device__ __forceinline__ float b2f(unsigned short h) {
    union { unsigned u; float f; } v; v.u = ((unsigned)h) << 16;
    return v.f;
}
__device__ __forceinline__ float b2f_lo(unsigned v) {  // low ushort of packed pair
    union { unsigned u; float f; } t; t.u = v << 16; return t.f;
}
__device__ __forceinline__ float b2f_hi(unsigned v) {
    union { unsigned u; float f; } t; t.u = v & 0xFFFF0000u; return t.f;
}

// rotated LDS chunk addressing (chunk = 16B = 8 bf16), zero-waste bank pad.
#define SFCH(r, c)  ((r) * 32 + (((c) + (r)) & 31))   // 64 rows x 32 chunks (256 cols)
#define SH1CH(r, c) ((r) * 16 + (((c) + (r)) & 15))   // 64 rows x 16 chunks (128 cols)
#define SH2CH(r, c) ((r) * 64 + (((c) + (r)) & 63))   // 64 rows x 64 chunks (512 cols)

// ---------------------------------------------------------------- transpose (proj weights only)
struct TDesc { const float* s; float* d; int R; int C; };
struct TPack { TDesc t[2]; };

__global__ __launch_bounds__(256) void transpose_all(TPack p) {
    TDesc d = p.t[blockIdx.y];
    int n = d.R * d.C;
    for (int i = blockIdx.x * 256 + threadIdx.x; i < n; i += gridDim.x * 256) {
        int r = i / d.C, c = i - r * d.C;
        d.d[c * d.R + r] = d.s[i];  // dst[k][h] = src[h][k]
    }
}

// ---------------------------------------------------------------- pack decoder weights into MFMA B-frag order
__global__ __launch_bounds__(256) void pack_weights(const float* __restrict__ W1,
                                                    const float* __restrict__ W2,
                                                    unsigned short* __restrict__ W1p,
                                                    unsigned short* __restrict__ W2p) {
    const int n = 512 * 256;
    for (int i = blockIdx.x * 256 + threadIdx.x; i < n; i += gridDim.x * 256) {
        int j = i & 7, lane = (i >> 3) & 63;
        int ln = lane & 15, lq = lane >> 4;
        int kg1 = (i >> 9) & 7,  t1 = i >> 12;
        W1p[i] = f2b(W1[(t1 * 16 + ln) * 256 + kg1 * 32 + lq * 8 + j]);
        int kg2 = (i >> 9) & 15, t2 = i >> 13;
        W2p[i] = f2b(W2[(t2 * 16 + ln) * 512 + kg2 * 32 + lq * 8 + j]);
    }
}

// ---------------------------------------------------------------- pack 8 sage weights (H x H) into B-frag order
struct SPack { const float* w[8]; };
__global__ __launch_bounds__(256) void pack_sage(SPack sp, unsigned short* __restrict__ out) {
    const int n = 8 * 16384;
    for (int i = blockIdx.x * 256 + threadIdx.x; i < n; i += gridDim.x * 256) {
        int j = i & 7, lane = (i >> 3) & 63;
        int kg = (i >> 9) & 3, t = (i >> 11) & 7, wsel = i >> 14;
        int ln = lane & 15, lq = lane >> 4;
        out[i] = f2b(sp.w[wsel][(t * 16 + ln) * H + kg * 32 + lq * 8 + j]);
    }
}

// ---------------------------------------------------------------- CSR build
__global__ __launch_bounds__(256) void deg_kernel(const int* __restrict__ ei,
                                                  int* rp_m, int* rp_u) {
    for (int i = blockIdx.x * 256 + threadIdx.x; i < NE; i += gridDim.x * 256) {
        int u = ei[i], m = ei[NE + i];
        atomicAdd(&rp_u[u + 1], 1);
        atomicAdd(&rp_m[m + 1], 1);
    }
}

__global__ __launch_bounds__(256) void scan2_kernel(int* rp_m, int n_m,
                                                    int* rp_u, int n_u) {
    int* a = (blockIdx.x == 0) ? rp_m : rp_u;
    int n  = (blockIdx.x == 0) ? n_m : n_u;
    __shared__ int s[256];
    __shared__ int carry;
    int tid = threadIdx.x;
    if (tid == 0) carry = 0;
    __syncthreads();
    for (int base = 0; base < n; base += 4096) {
        int v[16];
        int run = 0;
        int i0 = base + tid * 16;
#pragma unroll
        for (int i = 0; i < 16; ++i) {
            int x = (i0 + i < n) ? a[i0 + i] : 0;
            run += x; v[i] = run;
        }
        s[tid] = run;
        __syncthreads();
        for (int off = 1; off < 256; off <<= 1) {
            int t = (tid >= off) ? s[tid - off] : 0;
            __syncthreads();
            s[tid] += t;
            __syncthreads();
        }
        int prev = carry + (tid > 0 ? s[tid - 1] : 0);
#pragma unroll
        for (int i = 0; i < 16; ++i)
            if (i0 + i < n) a[i0 + i] = v[i] + prev;
        int total = s[255];
        __syncthreads();
        if (tid == 0) carry += total;
        __syncthreads();
    }
}

__global__ __launch_bounds__(256) void bucket_kernel(const int* __restrict__ ei,
        const int* __restrict__ rp_m, const int* __restrict__ rp_u,
        int* cur_m, int* cur_u, int* es_m, int* es_u) {
    for (int i = blockIdx.x * 256 + threadIdx.x; i < NE; i += gridDim.x * 256) {
        int u = ei[i], m = ei[NE + i];
        int pm = atomicAdd(&cur_m[m], 1);
        es_m[rp_m[m] + pm] = u;
        int pu = atomicAdd(&cur_u[u], 1);
        es_u[rp_u[u] + pu] = m;
    }
}

// ---------------------------------------------------------------- projection (Linear + BN(eval) + ReLU) -> bf16
template <int K>
__global__ __launch_bounds__(256, 2) void proj_kernel(
        const float* __restrict__ x, const float* __restrict__ Wt,
        const float* __restrict__ lb, const float* __restrict__ g,
        const float* __restrict__ bb, const float* __restrict__ bm,
        const float* __restrict__ bv, unsigned short* __restrict__ out, int N) {
    __shared__ float sA[64 * K];
    const int tid = threadIdx.x;
    const int row0 = blockIdx.x * 64;
    constexpr int F4 = K / 4;
#pragma unroll
    for (int i = 0; i < (64 * F4) / 256; ++i) {
        int idx = tid + i * 256;
        int r = idx / F4, c = idx - r * F4;
        int gr = min(row0 + r, N - 1);
        ((float4*)sA)[idx] = ((const float4*)(x + (size_t)gr * K))[c];
    }
    __syncthreads();
    const int h_t = tid & 31, r_t = tid >> 5;
    float acc[8][4] = {};
#pragma unroll 4
    for (int k = 0; k < K; k += 4) {
        float4 w[4];
#pragma unroll
        for (int kk = 0; kk < 4; ++kk)
            w[kk] = *(const float4*)(Wt + (k + kk) * H + h_t * 4);
#pragma unroll
        for (int rr = 0; rr < 8; ++rr) {
            float4 a = *(const float4*)(sA + (r_t * 8 + rr) * K + k);
            acc[rr][0] += a.x * w[0].x + a.y * w[1].x + a.z * w[2].x + a.w * w[3].x;
            acc[rr][1] += a.x * w[0].y + a.y * w[1].y + a.z * w[2].y + a.w * w[3].y;
            acc[rr][2] += a.x * w[0].z + a.y * w[1].z + a.z * w[2].z + a.w * w[3].z;
            acc[rr][3] += a.x * w[0].w + a.y * w[1].w + a.z * w[2].w + a.w * w[3].w;
        }
    }
    const int h = h_t * 4;
    float4 lb4 = *(const float4*)(lb + h);
    float4 g4  = *(const float4*)(g  + h);
    float4 bb4 = *(const float4*)(bb + h);
    float4 m4  = *(const float4*)(bm + h);
    float4 v4  = *(const float4*)(bv + h);
    float sc[4] = { g4.x * rsqrtf(v4.x + 1e-5f), g4.y * rsqrtf(v4.y + 1e-5f),
                    g4.z * rsqrtf(v4.z + 1e-5f), g4.w * rsqrtf(v4.w + 1e-5f) };
    float lbv[4] = { lb4.x, lb4.y, lb4.z, lb4.w };
    float mv[4]  = { m4.x, m4.y, m4.z, m4.w };
    float bbv[4] = { bb4.x, bb4.y, bb4.z, bb4.w };
#pragma unroll
    for (int rr = 0; rr < 8; ++rr) {
        int gr = row0 + r_t * 8 + rr;
        if (gr < N) {
            u16x4 o;
#pragma unroll
            for (int c = 0; c < 4; ++c)
                o[c] = f2b(fmaxf((acc[rr][c] + lbv[c] - mv[c]) * sc[c] + bbv[c], 0.0f));
            *(u16x4*)(out + (size_t)gr * H + h) = o;
        }
    }
}

// ---------------------------------------------------------------- segment mean (bf16 in/out, fp32 acc)
// one WAVE per node; 8 row-loads in flight (latency-bound gather).
__global__ __launch_bounds__(256) void agg_bf16(
        const unsigned short* __restrict__ srcA, const int* __restrict__ esA,
        const int* __restrict__ rpA, unsigned short* __restrict__ outA, int nA,
        const unsigned short* __restrict__ srcB, const int* __restrict__ esB,
        const int* __restrict__ rpB, unsigned short* __restrict__ outB, int nB) {
    int wid = blockIdx.x * 4 + (threadIdx.x >> 6);
    const int lane = threadIdx.x & 63;
    const unsigned short* src; const int* es; const int* rp; unsigned short* out; int n;
    if (wid < nA) { src = srcA; es = esA; rp = rpA; out = outA; n = wid; }
    else {
        wid -= nA;
        if (wid >= nB) return;
        src = srcB; es = esB; rp = rpB; out = outB; n = wid;
    }
    const int start = rp[n], end = rp[n + 1];
    float a0 = 0.0f, a1 = 0.0f;
    int j = start;
    for (; j + 8 <= end; j += 8) {
        unsigned v[8];
#pragma unroll
        for (int q = 0; q < 8; ++q)
            v[q] = *(const unsigned*)(src + (size_t)es[j + q] * H + lane * 2);
#pragma unroll
        for (int q = 0; q < 8; ++q) { a0 += b2f_lo(v[q]); a1 += b2f_hi(v[q]); }
    }
    for (; j < end; ++j) {
        unsigned v = *(const unsigned*)(src + (size_t)es[j] * H + lane * 2);
        a0 += b2f_lo(v); a1 += b2f_hi(v);
    }
    float inv = (end > start) ? 1.0f / (float)(end - start) : 0.0f;
    unsigned o = (unsigned)f2b(a0 * inv) | ((unsigned)f2b(a1 * inv) << 16);
    *(unsigned*)(out + (size_t)n * H + lane * 2) = o;
}

// ---------------------------------------------------------------- SAGE via MFMA
__global__ __launch_bounds__(256, 4) void sage_mfma(
        const unsigned short* __restrict__ aggA, const unsigned short* __restrict__ xA,
        const unsigned short* __restrict__ WlA, const unsigned short* __restrict__ WrA,
        const float* __restrict__ blA, unsigned short* __restrict__ outA, int NA, int NBLKA,
        const unsigned short* __restrict__ aggB, const unsigned short* __restrict__ xB,
        const unsigned short* __restrict__ WlB, const unsigned short* __restrict__ WrB,
        const float* __restrict__ blB, unsigned short* __restrict__ outB, int NB,
        int relu) {
    __shared__ unsigned short sAg[64 * 16 * 8];  // 16 KB
    __shared__ unsigned short sX[64 * 16 * 8];   // 16 KB
    const int tid = threadIdx.x;
    const unsigned short *agg, *x, *Wl, *Wr; const float* bl; unsigned short* out;
    int N, row0;
    if ((int)blockIdx.x < NBLKA) {
        agg = aggA; x = xA; Wl = WlA; Wr = WrA; bl = blA; out = outA; N = NA;
        row0 = blockIdx.x * 64;
    } else {
        agg = aggB; x = xB; Wl = WlB; Wr = WrB; bl = blB; out = outB; N = NB;
        row0 = (blockIdx.x - NBLKA) * 64;
    }
#pragma unroll
    for (int i = 0; i < 4; ++i) {
        int idx = tid + i * 256;           // 1024 chunks
        int r = idx >> 4, c = idx & 15;
        int gr = min(row0 + r, N - 1);
        *(u16x8*)(sAg + SH1CH(r, c) * 8) = *(const u16x8*)(agg + (size_t)gr * H + c * 8);
        *(u16x8*)(sX  + SH1CH(r, c) * 8) = *(const u16x8*)(x   + (size_t)gr * H + c * 8);
    }
    __syncthreads();
    const int lane = tid & 63, w = tid >> 6;
    const int ln = lane & 15, lq = lane >> 4;
    floatx4 acc[2][4] = {};
#pragma unroll 2
    for (int kg = 0; kg < 4; ++kg) {
        bf16x8 aA[4], aX[4];
#pragma unroll
        for (int mt = 0; mt < 4; ++mt) {
            aA[mt] = *(const bf16x8*)(sAg + SH1CH(mt * 16 + ln, kg * 4 + lq) * 8);
            aX[mt] = *(const bf16x8*)(sX  + SH1CH(mt * 16 + ln, kg * 4 + lq) * 8);
        }
#pragma unroll
        for (int nt = 0; nt < 2; ++nt) {
            int widx = ((w * 2 + nt) * 4 + kg) * 512 + lane * 8;
            bf16x8 bL = *(const bf16x8*)(Wl + widx);
            bf16x8 bR = *(const bf16x8*)(Wr + widx);
#pragma unroll
            for (int mt = 0; mt < 4; ++mt) {
                acc[nt][mt] = __builtin_amdgcn_mfma_f32_16x16x32_bf16(aA[mt], bL, acc[nt][mt], 0, 0, 0);
                acc[nt][mt] = __builtin_amdgcn_mfma_f32_16x16x32_bf16(aX[mt], bR, acc[nt][mt], 0, 0, 0);
            }
        }
    }
    __syncthreads();   // done reading sAg; reuse it for output staging
    {
#pragma unroll
        for (int nt = 0; nt < 2; ++nt) {
            int ncol = w * 32 + nt * 16 + ln;   // 0..127
            float bv = bl[ncol];
            int cch = ncol >> 3, coff = ncol & 7;
#pragma unroll
            for (int mt = 0; mt < 4; ++mt)
#pragma unroll
                for (int i = 0; i < 4; ++i) {
                    int row = mt * 16 + lq * 4 + i;
                    float v = acc[nt][mt][i] + bv;
                    if (relu) v = fmaxf(v, 0.0f);
                    sAg[SH1CH(row, cch) * 8 + coff] = f2b(v);
                }
        }
    }
    __syncthreads();
#pragma unroll
    for (int i = 0; i < 4; ++i) {
        int idx = tid + i * 256;
        int r = idx >> 4, c = idx & 15;
        int gr = row0 + r;
        if (gr < N)
            *(u16x8*)(out + (size_t)gr * H + c * 8) = *(const u16x8*)(sAg + SH1CH(r, c) * 8);
    }
}

// ---------------------------------------------------------------- fused edge decoder MLP — 3-phase
// Phase 1: ALL of h1 (64x512 bf16, 64 KB LDS) with only acc1[2][4]=32 AGPR live;
//          the two n-halves write disjoint sH1 ranges -> no barrier between them.
// Phase 2: layer 2 over full K=512 with only acc3[2][4]=32 AGPR live.
// Phase 3: h2 -> out.
// Peak live accumulator 32 AGPR (vs 64 in R5-R8) -> fits __launch_bounds__(512,4)'s
// 128 unified regs/wave with NO scratch spill. 3 barriers total. LDS 96 KB (1 blk/CU).
__global__ __launch_bounds__(512, 4) void decoder_mfma(
        const unsigned short* __restrict__ zu, const unsigned short* __restrict__ zm,
        const int* __restrict__ eli,
        const unsigned short* __restrict__ W1p, const float* __restrict__ b1,
        const unsigned short* __restrict__ W2p, const float* __restrict__ b2,
        const float* __restrict__ W3, const float* __restrict__ b3,
        float* __restrict__ out) {
    __shared__ unsigned short sF[64 * 32 * 8];   // feat 64x256 bf16 rotated (32 KB), later h2
    __shared__ unsigned short sH1[64 * 64 * 8];  // h1 FULL 64x512 bf16 rotated (64 KB)
    const int tid = threadIdx.x;
    const int row0 = blockIdx.x * 64;
    // ---- gather feat = [zu[eu] | zm[em]] (bf16 straight copy)
    {
        int r = tid >> 3, p = tid & 7;
        int rg = min(row0 + r, NL - 1);
        int iu = eli[rg], im = eli[NL + rg];
        const unsigned short* zur = zu + (size_t)iu * H;
        const unsigned short* zmr = zm + (size_t)im * H;
#pragma unroll
        for (int j = 0; j < 4; ++j) {
            int c = p + j * 8;   // 0..31
            const unsigned short* s = (c < 16) ? (zur + c * 8) : (zmr + (c - 16) * 8);
            *(u16x8*)(sF + SFCH(r, c) * 8) = *(const u16x8*)s;
        }
    }
    __syncthreads();
    const int lane = tid & 63, w = tid >> 6;   // 8 waves
    const int ln = lane & 15, lq = lane >> 4;
    // ---- phase 1: full h1; only acc1 live
#pragma unroll 1
    for (int h = 0; h < 2; ++h) {
        floatx4 acc1[2][4] = {};
        const unsigned short* w1base = W1p + ((size_t)(h * 16 + w * 2) * 8) * 512 + lane * 8;
#pragma unroll 2
        for (int kg = 0; kg < 8; ++kg) {
            bf16x8 a[4];
#pragma unroll
            for (int mt = 0; mt < 4; ++mt)
                a[mt] = *(const bf16x8*)(sF + SFCH(mt * 16 + ln, kg * 4 + lq) * 8);
#pragma unroll
            for (int nt = 0; nt < 2; ++nt) {
                bf16x8 b = *(const bf16x8*)(w1base + (size_t)(nt * 8 + kg) * 512);
#pragma unroll
                for (int mt = 0; mt < 4; ++mt)
                    acc1[nt][mt] = __builtin_amdgcn_mfma_f32_16x16x32_bf16(a[mt], b, acc1[nt][mt], 0, 0, 0);
            }
        }
        // epilogue: +b1, ReLU, store to FULL sH1 at cols h*256 + w*32 + nt*16 + ln
#pragma unroll
        for (int nt = 0; nt < 2; ++nt) {
            int ncol = h * 256 + w * 32 + nt * 16 + ln;   // 0..511
            float bv = b1[ncol];
            int cch = ncol >> 3, coff = ncol & 7;
#pragma unroll
            for (int mt = 0; mt < 4; ++mt)
#pragma unroll
                for (int i = 0; i < 4; ++i) {
                    int row = mt * 16 + lq * 4 + i;
                    sH1[SH2CH(row, cch) * 8 + coff] = f2b(fmaxf(acc1[nt][mt][i] + bv, 0.0f));
                }
        }
    }
    __syncthreads();
    // ---- phase 2: layer 2 over full K=512; only acc3 live
    floatx4 acc3[2][4] = {};
    {
        const unsigned short* w2base = W2p + ((size_t)(w * 2) * 16) * 512 + lane * 8;
#pragma unroll 2
        for (int kg = 0; kg < 16; ++kg) {
            bf16x8 a[4];
#pragma unroll
            for (int mt = 0; mt < 4; ++mt)
                a[mt] = *(const bf16x8*)(sH1 + SH2CH(mt * 16 + ln, kg * 4 + lq) * 8);
#pragma unroll
            for (int nt = 0; nt < 2; ++nt) {
                bf16x8 b = *(const bf16x8*)(w2base + (size_t)(nt * 16 + kg) * 512);
#pragma unroll
                for (int mt = 0; mt < 4; ++mt)
                    acc3[nt][mt] = __builtin_amdgcn_mfma_f32_16x16x32_bf16(a[mt], b, acc3[nt][mt], 0, 0, 0);
            }
        }
    }
    // ---- h2 = ReLU(acc3 + b2) -> sF overlay (all sF reads completed before phase-1 barrier)
    {
#pragma unroll
        for (int nt = 0; nt < 2; ++nt) {
            int ncol = w * 32 + nt * 16 + ln;   // 0..255
            float bv = b2[ncol];
            int cch = ncol >> 3, coff = ncol & 7;
#pragma unroll
            for (int mt = 0; mt < 4; ++mt)
#pragma unroll
                for (int i = 0; i < 4; ++i) {
                    int row = mt * 16 + lq * 4 + i;
                    sF[SFCH(row, cch) * 8 + coff] = f2b(fmaxf(acc3[nt][mt][i] + bv, 0.0f));
                }
        }
    }
    __syncthreads();
    // ---- layer 3: out = h2 @ W3^T + b3
    {
        int r = tid >> 3, p = tid & 7;   // 64 rows x 8 threads (32 cols each)
        float sum = 0.0f;
#pragma unroll
        for (int j = 0; j < 4; ++j) {
            int c = p + j * 8;
            const unsigned short* hp = sF + SFCH(r, c) * 8;
            const float* w3p = W3 + c * 8;
#pragma unroll
            for (int e = 0; e < 8; ++e) sum += b2f(hp[e]) * w3p[e];
        }
        sum += __shfl_down(sum, 4, 8);
        sum += __shfl_down(sum, 2, 8);
        sum += __shfl_down(sum, 1, 8);
        if (p == 0 && row0 + r < NL) out[row0 + r] = sum + b3[0];
    }
}

// ---------------------------------------------------------------- host
extern "C" void kernel_launch(void* const* d_in, const int* in_sizes, int n_in,
                              void* d_out, int out_size, void* d_ws, size_t ws_size,
                              hipStream_t stream) {
    const float* x_user  = (const float*)d_in[0];
    const float* x_movie = (const float*)d_in[1];
    const int*   ei      = (const int*)d_in[2];
    const int*   eli     = (const int*)d_in[3];
    const float* lin_u_W = (const float*)d_in[4];
    const float* lin_u_b = (const float*)d_in[5];
    const float* lin_m_W = (const float*)d_in[6];
    const float* lin_m_b = (const float*)d_in[7];
    const float* bn_u_g  = (const float*)d_in[8];
    const float* bn_u_b  = (const float*)d_in[9];
    const float* bn_u_m  = (const float*)d_in[10];
    const float* bn_u_v  = (const float*)d_in[11];
    const float* bn_m_g  = (const float*)d_in[12];
    const float* bn_m_b  = (const float*)d_in[13];
    const float* bn_m_m  = (const float*)d_in[14];
    const float* bn_m_v  = (const float*)d_in[15];
    const float* c1_um_Wl = (const float*)d_in[16];
    const float* c1_um_bl = (const float*)d_in[17];
    const float* c1_um_Wr = (const float*)d_in[18];
    const float* c1_mu_Wl = (const float*)d_in[19];
    const float* c1_mu_bl = (const float*)d_in[20];
    const float* c1_mu_Wr = (const float*)d_in[21];
    const float* c2_um_Wl = (const float*)d_in[22];
    const float* c2_um_bl = (const float*)d_in[23];
    const float* c2_um_Wr = (const float*)d_in[24];
    const float* c2_mu_Wl = (const float*)d_in[25];
    const float* c2_mu_bl = (const float*)d_in[26];
    const float* c2_mu_Wr = (const float*)d_in[27];
    const float* dec_W1 = (const float*)d_in[28];
    const float* dec_b1 = (const float*)d_in[29];
    const float* dec_W2 = (const float*)d_in[30];
    const float* dec_b2 = (const float*)d_in[31];
    const float* dec_W3 = (const float*)d_in[32];
    const float* dec_b3 = (const float*)d_in[33];

    char* base = (char*)d_ws;
    size_t off = 0;
    auto alloc = [&](size_t bytes) -> char* {
        char* p = base + off;
        off += (bytes + 255) & ~(size_t)255;
        return p;
    };
    unsigned short* xu_b  = (unsigned short*)alloc((size_t)NU * H * 2);
    unsigned short* xm_b  = (unsigned short*)alloc((size_t)NM * H * 2);
    unsigned short* xu1_b = (unsigned short*)alloc((size_t)NU * H * 2);
    unsigned short* xm1_b = (unsigned short*)alloc((size_t)NM * H * 2);
    unsigned short* aggu  = (unsigned short*)alloc((size_t)NU * H * 2);
    unsigned short* aggm  = (unsigned short*)alloc((size_t)NM * H * 2);
    float* wt_u = (float*)alloc((size_t)64 * H * 4);
    float* wt_m = (float*)alloc((size_t)H * H * 4);
    unsigned short* wsg = (unsigned short*)alloc((size_t)8 * 16384 * 2);  // packed sage weights
    unsigned short* w1p = (unsigned short*)alloc((size_t)512 * 256 * 2);
    unsigned short* w2p = (unsigned short*)alloc((size_t)256 * 512 * 2);
    int* rp_m  = (int*)alloc((size_t)(NM + 1) * 4);
    int* rp_u  = (int*)alloc((size_t)(NU + 1) * 4);
    int* cur_m = (int*)alloc((size_t)NM * 4);
    int* cur_u = (int*)alloc((size_t)NU * 4);
    int* es_m  = (int*)alloc((size_t)NE * 4);
    int* es_u  = (int*)alloc((size_t)NE * 4);
    unsigned short* zu = xu_b;   // xu_b dead after conv1 sage -> reuse
    unsigned short* zm = xm_b;

    // zero CSR meta (rp_m .. cur_u incl. padding)
    hipMemsetAsync(rp_m, 0, (size_t)((char*)es_m - (char*)rp_m), stream);

    TPack tp;
    tp.t[0] = { lin_u_W, wt_u, H, 64 };
    tp.t[1] = { lin_m_W, wt_m, H, H };
    transpose_all<<<dim3(64, 2), 256, 0, stream>>>(tp);
    pack_weights<<<256, 256, 0, stream>>>(dec_W1, dec_W2, w1p, w2p);
    SPack sp;
    sp.w[0] = c1_um_Wl; sp.w[1] = c1_um_Wr; sp.w[2] = c1_mu_Wl; sp.w[3] = c1_mu_Wr;
    sp.w[4] = c2_um_Wl; sp.w[5] = c2_um_Wr; sp.w[6] = c2_mu_Wl; sp.w[7] = c2_mu_Wr;
    pack_sage<<<128, 256, 0, stream>>>(sp, wsg);
    const unsigned short* W_c1um_l = wsg + 0 * 16384;
    const unsigned short* W_c1um_r = wsg + 1 * 16384;
    const unsigned short* W_c1mu_l = wsg + 2 * 16384;
    const unsigned short* W_c1mu_r = wsg + 3 * 16384;
    const unsigned short* W_c2um_l = wsg + 4 * 16384;
    const unsigned short* W_c2um_r = wsg + 5 * 16384;
    const unsigned short* W_c2mu_l = wsg + 6 * 16384;
    const unsigned short* W_c2mu_r = wsg + 7 * 16384;

    deg_kernel<<<2048, 256, 0, stream>>>(ei, rp_m, rp_u);
    scan2_kernel<<<2, 256, 0, stream>>>(rp_m, NM + 1, rp_u, NU + 1);
    bucket_kernel<<<2048, 256, 0, stream>>>(ei, rp_m, rp_u, cur_m, cur_u, es_m, es_u);

    proj_kernel<64><<<(NU + 63) / 64, 256, 0, stream>>>(
        x_user, wt_u, lin_u_b, bn_u_g, bn_u_b, bn_u_m, bn_u_v, xu_b, NU);
    proj_kernel<128><<<(NM + 63) / 64, 256, 0, stream>>>(
        x_movie, wt_m, lin_m_b, bn_m_g, bn_m_b, bn_m_m, bn_m_v, xm_b, NM);

    const int AGG_BLOCKS = (NM + NU + 3) / 4;
    const int NBLK_M = (NM + 63) / 64, NBLK_U = (NU + 63) / 64;

    // conv1
    agg_bf16<<<AGG_BLOCKS, 256, 0, stream>>>(xu_b, es_m, rp_m, aggm, NM,
                                             xm_b, es_u, rp_u, aggu, NU);
    sage_mfma<<<NBLK_M + NBLK_U, 256, 0, stream>>>(
        aggm, xm_b, W_c1um_l, W_c1um_r, c1_um_bl, xm1_b, NM, NBLK_M,
        aggu, xu_b, W_c1mu_l, W_c1mu_r, c1_mu_bl, xu1_b, NU, 1);
    // conv2
    agg_bf16<<<AGG_BLOCKS, 256, 0, stream>>>(xu1_b, es_m, rp_m, aggm, NM,
                                             xm1_b, es_u, rp_u, aggu, NU);
    sage_mfma<<<NBLK_M + NBLK_U, 256, 0, stream>>>(
        aggm, xm1_b, W_c2um_l, W_c2um_r, c2_um_bl, zm, NM, NBLK_M,
        aggu, xu1_b, W_c2mu_l, W_c2mu_r, c2_mu_bl, zu, NU, 0);

    // decoder (bf16 MFMA, 3-phase fused 3-layer MLP, 96 KB LDS, no spill)
    decoder_mfma<<<(NL + 63) / 64, 512, 0, stream>>>(
        zu, zm, eli, w1p, dec_b1, w2p, dec_b2, dec_W3, dec_b3, (float*)d_out);
}

// Round 10
// 1315.258 us; speedup vs baseline: 1.0838x; 1.0019x over previous
//
#include <hip/hip_runtime.h>

#define NU 100000
#define NM 20000
#define NE 2000000
#define NL 500000
#define H  128

typedef __attribute__((ext_vector_type(8))) short bf16x8;            // 8 bf16 (4 VGPRs)
typedef __attribute__((ext_vector_type(4))) float floatx4;           // 4 fp32 acc
typedef __attribute__((ext_vector_type(8))) unsigned short u16x8;    // 16B load/store
typedef __attribute__((ext_vector_type(4))) unsigned short u16x4;    // 8B store

__device__ __forceinline__ unsigned short f2b(float x) {
    union { float f; unsigned u; } v; v.f = x;
    unsigned r = v.u + 0x7FFFu + ((v.u >> 16) & 1u);  // RNE
    return (unsigned short)(r >> 16);
}
__device__ __forceinline__ float b2f(unsigned short h) {
    union { unsigned u; float f; } v; v.u = ((unsigned)h) << 16;
    return v.f;
}
__device__ __forceinline__ float b2f_lo(unsigned v) {  // low ushort of packed pair
    union { unsigned u; float f; } t; t.u = v << 16; return t.f;
}
__device__ __forceinline__ float b2f_hi(unsigned v) {
    union { unsigned u; float f; } t; t.u = v & 0xFFFF0000u; return t.f;
}

// rotated LDS chunk addressing (chunk = 16B = 8 bf16), zero-waste bank pad.
#define SFCH(r, c)  ((r) * 32 + (((c) + (r)) & 31))   // 64 rows x 32 chunks (256 cols)
#define SH1CH(r, c) ((r) * 16 + (((c) + (r)) & 15))   // 64 rows x 16 chunks (128 cols)
#define SH2CH(r, c) ((r) * 64 + (((c) + (r)) & 63))   // 64 rows x 64 chunks (512 cols)

// ---------------------------------------------------------------- transpose (proj weights only)
struct TDesc { const float* s; float* d; int R; int C; };
struct TPack { TDesc t[2]; };

__global__ __launch_bounds__(256) void transpose_all(TPack p) {
    TDesc d = p.t[blockIdx.y];
    int n = d.R * d.C;
    for (int i = blockIdx.x * 256 + threadIdx.x; i < n; i += gridDim.x * 256) {
        int r = i / d.C, c = i - r * d.C;
        d.d[c * d.R + r] = d.s[i];  // dst[k][h] = src[h][k]
    }
}

// ---------------------------------------------------------------- pack decoder weights into MFMA B-frag order
__global__ __launch_bounds__(256) void pack_weights(const float* __restrict__ W1,
                                                    const float* __restrict__ W2,
                                                    unsigned short* __restrict__ W1p,
                                                    unsigned short* __restrict__ W2p) {
    const int n = 512 * 256;
    for (int i = blockIdx.x * 256 + threadIdx.x; i < n; i += gridDim.x * 256) {
        int j = i & 7, lane = (i >> 3) & 63;
        int ln = lane & 15, lq = lane >> 4;
        int kg1 = (i >> 9) & 7,  t1 = i >> 12;
        W1p[i] = f2b(W1[(t1 * 16 + ln) * 256 + kg1 * 32 + lq * 8 + j]);
        int kg2 = (i >> 9) & 15, t2 = i >> 13;
        W2p[i] = f2b(W2[(t2 * 16 + ln) * 512 + kg2 * 32 + lq * 8 + j]);
    }
}

// ---------------------------------------------------------------- pack 8 sage weights (H x H) into B-frag order
struct SPack { const float* w[8]; };
__global__ __launch_bounds__(256) void pack_sage(SPack sp, unsigned short* __restrict__ out) {
    const int n = 8 * 16384;
    for (int i = blockIdx.x * 256 + threadIdx.x; i < n; i += gridDim.x * 256) {
        int j = i & 7, lane = (i >> 3) & 63;
        int kg = (i >> 9) & 3, t = (i >> 11) & 7, wsel = i >> 14;
        int ln = lane & 15, lq = lane >> 4;
        out[i] = f2b(sp.w[wsel][(t * 16 + ln) * H + kg * 32 + lq * 8 + j]);
    }
}

// ---------------------------------------------------------------- CSR build
__global__ __launch_bounds__(256) void deg_kernel(const int* __restrict__ ei,
                                                  int* rp_m, int* rp_u) {
    for (int i = blockIdx.x * 256 + threadIdx.x; i < NE; i += gridDim.x * 256) {
        int u = ei[i], m = ei[NE + i];
        atomicAdd(&rp_u[u + 1], 1);
        atomicAdd(&rp_m[m + 1], 1);
    }
}

__global__ __launch_bounds__(256) void scan2_kernel(int* rp_m, int n_m,
                                                    int* rp_u, int n_u) {
    int* a = (blockIdx.x == 0) ? rp_m : rp_u;
    int n  = (blockIdx.x == 0) ? n_m : n_u;
    __shared__ int s[256];
    __shared__ int carry;
    int tid = threadIdx.x;
    if (tid == 0) carry = 0;
    __syncthreads();
    for (int base = 0; base < n; base += 4096) {
        int v[16];
        int run = 0;
        int i0 = base + tid * 16;
#pragma unroll
        for (int i = 0; i < 16; ++i) {
            int x = (i0 + i < n) ? a[i0 + i] : 0;
            run += x; v[i] = run;
        }
        s[tid] = run;
        __syncthreads();
        for (int off = 1; off < 256; off <<= 1) {
            int t = (tid >= off) ? s[tid - off] : 0;
            __syncthreads();
            s[tid] += t;
            __syncthreads();
        }
        int prev = carry + (tid > 0 ? s[tid - 1] : 0);
#pragma unroll
        for (int i = 0; i < 16; ++i)
            if (i0 + i < n) a[i0 + i] = v[i] + prev;
        int total = s[255];
        __syncthreads();
        if (tid == 0) carry += total;
        __syncthreads();
    }
}

__global__ __launch_bounds__(256) void bucket_kernel(const int* __restrict__ ei,
        const int* __restrict__ rp_m, const int* __restrict__ rp_u,
        int* cur_m, int* cur_u, int* es_m, int* es_u) {
    for (int i = blockIdx.x * 256 + threadIdx.x; i < NE; i += gridDim.x * 256) {
        int u = ei[i], m = ei[NE + i];
        int pm = atomicAdd(&cur_m[m], 1);
        es_m[rp_m[m] + pm] = u;
        int pu = atomicAdd(&cur_u[u], 1);
        es_u[rp_u[u] + pu] = m;
    }
}

// ---------------------------------------------------------------- projection (Linear + BN(eval) + ReLU) -> bf16
template <int K>
__global__ __launch_bounds__(256, 2) void proj_kernel(
        const float* __restrict__ x, const float* __restrict__ Wt,
        const float* __restrict__ lb, const float* __restrict__ g,
        const float* __restrict__ bb, const float* __restrict__ bm,
        const float* __restrict__ bv, unsigned short* __restrict__ out, int N) {
    __shared__ float sA[64 * K];
    const int tid = threadIdx.x;
    const int row0 = blockIdx.x * 64;
    constexpr int F4 = K / 4;
#pragma unroll
    for (int i = 0; i < (64 * F4) / 256; ++i) {
        int idx = tid + i * 256;
        int r = idx / F4, c = idx - r * F4;
        int gr = min(row0 + r, N - 1);
        ((float4*)sA)[idx] = ((const float4*)(x + (size_t)gr * K))[c];
    }
    __syncthreads();
    const int h_t = tid & 31, r_t = tid >> 5;
    float acc[8][4] = {};
#pragma unroll 4
    for (int k = 0; k < K; k += 4) {
        float4 w[4];
#pragma unroll
        for (int kk = 0; kk < 4; ++kk)
            w[kk] = *(const float4*)(Wt + (k + kk) * H + h_t * 4);
#pragma unroll
        for (int rr = 0; rr < 8; ++rr) {
            float4 a = *(const float4*)(sA + (r_t * 8 + rr) * K + k);
            acc[rr][0] += a.x * w[0].x + a.y * w[1].x + a.z * w[2].x + a.w * w[3].x;
            acc[rr][1] += a.x * w[0].y + a.y * w[1].y + a.z * w[2].y + a.w * w[3].y;
            acc[rr][2] += a.x * w[0].z + a.y * w[1].z + a.z * w[2].z + a.w * w[3].z;
            acc[rr][3] += a.x * w[0].w + a.y * w[1].w + a.z * w[2].w + a.w * w[3].w;
        }
    }
    const int h = h_t * 4;
    float4 lb4 = *(const float4*)(lb + h);
    float4 g4  = *(const float4*)(g  + h);
    float4 bb4 = *(const float4*)(bb + h);
    float4 m4  = *(const float4*)(bm + h);
    float4 v4  = *(const float4*)(bv + h);
    float sc[4] = { g4.x * rsqrtf(v4.x + 1e-5f), g4.y * rsqrtf(v4.y + 1e-5f),
                    g4.z * rsqrtf(v4.z + 1e-5f), g4.w * rsqrtf(v4.w + 1e-5f) };
    float lbv[4] = { lb4.x, lb4.y, lb4.z, lb4.w };
    float mv[4]  = { m4.x, m4.y, m4.z, m4.w };
    float bbv[4] = { bb4.x, bb4.y, bb4.z, bb4.w };
#pragma unroll
    for (int rr = 0; rr < 8; ++rr) {
        int gr = row0 + r_t * 8 + rr;
        if (gr < N) {
            u16x4 o;
#pragma unroll
            for (int c = 0; c < 4; ++c)
                o[c] = f2b(fmaxf((acc[rr][c] + lbv[c] - mv[c]) * sc[c] + bbv[c], 0.0f));
            *(u16x4*)(out + (size_t)gr * H + h) = o;
        }
    }
}

// ---------------------------------------------------------------- segment mean (bf16 in/out, fp32 acc)
// one WAVE per node; 8 row-loads in flight (latency-bound gather).
__global__ __launch_bounds__(256) void agg_bf16(
        const unsigned short* __restrict__ srcA, const int* __restrict__ esA,
        const int* __restrict__ rpA, unsigned short* __restrict__ outA, int nA,
        const unsigned short* __restrict__ srcB, const int* __restrict__ esB,
        const int* __restrict__ rpB, unsigned short* __restrict__ outB, int nB) {
    int wid = blockIdx.x * 4 + (threadIdx.x >> 6);
    const int lane = threadIdx.x & 63;
    const unsigned short* src; const int* es; const int* rp; unsigned short* out; int n;
    if (wid < nA) { src = srcA; es = esA; rp = rpA; out = outA; n = wid; }
    else {
        wid -= nA;
        if (wid >= nB) return;
        src = srcB; es = esB; rp = rpB; out = outB; n = wid;
    }
    const int start = rp[n], end = rp[n + 1];
    float a0 = 0.0f, a1 = 0.0f;
    int j = start;
    for (; j + 8 <= end; j += 8) {
        unsigned v[8];
#pragma unroll
        for (int q = 0; q < 8; ++q)
            v[q] = *(const unsigned*)(src + (size_t)es[j + q] * H + lane * 2);
#pragma unroll
        for (int q = 0; q < 8; ++q) { a0 += b2f_lo(v[q]); a1 += b2f_hi(v[q]); }
    }
    for (; j < end; ++j) {
        unsigned v = *(const unsigned*)(src + (size_t)es[j] * H + lane * 2);
        a0 += b2f_lo(v); a1 += b2f_hi(v);
    }
    float inv = (end > start) ? 1.0f / (float)(end - start) : 0.0f;
    unsigned o = (unsigned)f2b(a0 * inv) | ((unsigned)f2b(a1 * inv) << 16);
    *(unsigned*)(out + (size_t)n * H + lane * 2) = o;
}

// ---------------------------------------------------------------- SAGE via MFMA
__global__ __launch_bounds__(256, 4) void sage_mfma(
        const unsigned short* __restrict__ aggA, const unsigned short* __restrict__ xA,
        const unsigned short* __restrict__ WlA, const unsigned short* __restrict__ WrA,
        const float* __restrict__ blA, unsigned short* __restrict__ outA, int NA, int NBLKA,
        const unsigned short* __restrict__ aggB, const unsigned short* __restrict__ xB,
        const unsigned short* __restrict__ WlB, const unsigned short* __restrict__ WrB,
        const float* __restrict__ blB, unsigned short* __restrict__ outB, int NB,
        int relu) {
    __shared__ unsigned short sAg[64 * 16 * 8];  // 16 KB
    __shared__ unsigned short sX[64 * 16 * 8];   // 16 KB
    const int tid = threadIdx.x;
    const unsigned short *agg, *x, *Wl, *Wr; const float* bl; unsigned short* out;
    int N, row0;
    if ((int)blockIdx.x < NBLKA) {
        agg = aggA; x = xA; Wl = WlA; Wr = WrA; bl = blA; out = outA; N = NA;
        row0 = blockIdx.x * 64;
    } else {
        agg = aggB; x = xB; Wl = WlB; Wr = WrB; bl = blB; out = outB; N = NB;
        row0 = (blockIdx.x - NBLKA) * 64;
    }
#pragma unroll
    for (int i = 0; i < 4; ++i) {
        int idx = tid + i * 256;           // 1024 chunks
        int r = idx >> 4, c = idx & 15;
        int gr = min(row0 + r, N - 1);
        *(u16x8*)(sAg + SH1CH(r, c) * 8) = *(const u16x8*)(agg + (size_t)gr * H + c * 8);
        *(u16x8*)(sX  + SH1CH(r, c) * 8) = *(const u16x8*)(x   + (size_t)gr * H + c * 8);
    }
    __syncthreads();
    const int lane = tid & 63, w = tid >> 6;
    const int ln = lane & 15, lq = lane >> 4;
    floatx4 acc[2][4] = {};
#pragma unroll 2
    for (int kg = 0; kg < 4; ++kg) {
        bf16x8 aA[4], aX[4];
#pragma unroll
        for (int mt = 0; mt < 4; ++mt) {
            aA[mt] = *(const bf16x8*)(sAg + SH1CH(mt * 16 + ln, kg * 4 + lq) * 8);
            aX[mt] = *(const bf16x8*)(sX  + SH1CH(mt * 16 + ln, kg * 4 + lq) * 8);
        }
#pragma unroll
        for (int nt = 0; nt < 2; ++nt) {
            int widx = ((w * 2 + nt) * 4 + kg) * 512 + lane * 8;
            bf16x8 bL = *(const bf16x8*)(Wl + widx);
            bf16x8 bR = *(const bf16x8*)(Wr + widx);
#pragma unroll
            for (int mt = 0; mt < 4; ++mt) {
                acc[nt][mt] = __builtin_amdgcn_mfma_f32_16x16x32_bf16(aA[mt], bL, acc[nt][mt], 0, 0, 0);
                acc[nt][mt] = __builtin_amdgcn_mfma_f32_16x16x32_bf16(aX[mt], bR, acc[nt][mt], 0, 0, 0);
            }
        }
    }
    __syncthreads();   // done reading sAg; reuse it for output staging
    {
#pragma unroll
        for (int nt = 0; nt < 2; ++nt) {
            int ncol = w * 32 + nt * 16 + ln;   // 0..127
            float bv = bl[ncol];
            int cch = ncol >> 3, coff = ncol & 7;
#pragma unroll
            for (int mt = 0; mt < 4; ++mt)
#pragma unroll
                for (int i = 0; i < 4; ++i) {
                    int row = mt * 16 + lq * 4 + i;
                    float v = acc[nt][mt][i] + bv;
                    if (relu) v = fmaxf(v, 0.0f);
                    sAg[SH1CH(row, cch) * 8 + coff] = f2b(v);
                }
        }
    }
    __syncthreads();
#pragma unroll
    for (int i = 0; i < 4; ++i) {
        int idx = tid + i * 256;
        int r = idx >> 4, c = idx & 15;
        int gr = row0 + r;
        if (gr < N)
            *(u16x8*)(out + (size_t)gr * H + c * 8) = *(const u16x8*)(sAg + SH1CH(r, c) * 8);
    }
}

// ---------------------------------------------------------------- fused edge decoder MLP — 3-phase, nt=4
// LDS (96 KB) caps residency at 1 block/CU = 2 waves/SIMD REGARDLESS of
// launch_bounds, so declare (512,2) -> 256 unified regs/wave (free headroom;
// R9's (512,4) capped at 128 for no occupancy gain). Spend it on single-pass
// phase 1 with nt=4: acc1[4][4]=64 AGPR, each A-read feeds 4 MFMAs ->
// phase-1 LDS reads halve (512->256 b128/block; block total 1024->768).
__global__ __launch_bounds__(512, 2) void decoder_mfma(
        const unsigned short* __restrict__ zu, const unsigned short* __restrict__ zm,
        const int* __restrict__ eli,
        const unsigned short* __restrict__ W1p, const float* __restrict__ b1,
        const unsigned short* __restrict__ W2p, const float* __restrict__ b2,
        const float* __restrict__ W3, const float* __restrict__ b3,
        float* __restrict__ out) {
    __shared__ unsigned short sF[64 * 32 * 8];   // feat 64x256 bf16 rotated (32 KB), later h2
    __shared__ unsigned short sH1[64 * 64 * 8];  // h1 FULL 64x512 bf16 rotated (64 KB)
    const int tid = threadIdx.x;
    const int row0 = blockIdx.x * 64;
    // ---- gather feat = [zu[eu] | zm[em]] (bf16 straight copy)
    {
        int r = tid >> 3, p = tid & 7;
        int rg = min(row0 + r, NL - 1);
        int iu = eli[rg], im = eli[NL + rg];
        const unsigned short* zur = zu + (size_t)iu * H;
        const unsigned short* zmr = zm + (size_t)im * H;
#pragma unroll
        for (int j = 0; j < 4; ++j) {
            int c = p + j * 8;   // 0..31
            const unsigned short* s = (c < 16) ? (zur + c * 8) : (zmr + (c - 16) * 8);
            *(u16x8*)(sF + SFCH(r, c) * 8) = *(const u16x8*)s;
        }
    }
    __syncthreads();
    const int lane = tid & 63, w = tid >> 6;   // 8 waves
    const int ln = lane & 15, lq = lane >> 4;
    // ---- phase 1: full h1 in ONE pass; wave w owns n-cols [w*64, +64)
    {
        floatx4 acc1[4][4] = {};
        const unsigned short* w1base = W1p + ((size_t)(w * 4) * 8) * 512 + lane * 8;
#pragma unroll 2
        for (int kg = 0; kg < 8; ++kg) {
            bf16x8 a[4];
#pragma unroll
            for (int mt = 0; mt < 4; ++mt)
                a[mt] = *(const bf16x8*)(sF + SFCH(mt * 16 + ln, kg * 4 + lq) * 8);
#pragma unroll
            for (int nt = 0; nt < 4; ++nt) {
                bf16x8 b = *(const bf16x8*)(w1base + (size_t)(nt * 8 + kg) * 512);
#pragma unroll
                for (int mt = 0; mt < 4; ++mt)
                    acc1[nt][mt] = __builtin_amdgcn_mfma_f32_16x16x32_bf16(a[mt], b, acc1[nt][mt], 0, 0, 0);
            }
        }
        // epilogue: +b1, ReLU, store to sH1 at cols w*64 + nt*16 + ln
#pragma unroll
        for (int nt = 0; nt < 4; ++nt) {
            int ncol = w * 64 + nt * 16 + ln;   // 0..511
            float bv = b1[ncol];
            int cch = ncol >> 3, coff = ncol & 7;
#pragma unroll
            for (int mt = 0; mt < 4; ++mt)
#pragma unroll
                for (int i = 0; i < 4; ++i) {
                    int row = mt * 16 + lq * 4 + i;
                    sH1[SH2CH(row, cch) * 8 + coff] = f2b(fmaxf(acc1[nt][mt][i] + bv, 0.0f));
                }
        }
    }
    __syncthreads();
    // ---- phase 2: layer 2 over full K=512; only acc3 live
    floatx4 acc3[2][4] = {};
    {
        const unsigned short* w2base = W2p + ((size_t)(w * 2) * 16) * 512 + lane * 8;
#pragma unroll 2
        for (int kg = 0; kg < 16; ++kg) {
            bf16x8 a[4];
#pragma unroll
            for (int mt = 0; mt < 4; ++mt)
                a[mt] = *(const bf16x8*)(sH1 + SH2CH(mt * 16 + ln, kg * 4 + lq) * 8);
#pragma unroll
            for (int nt = 0; nt < 2; ++nt) {
                bf16x8 b = *(const bf16x8*)(w2base + (size_t)(nt * 16 + kg) * 512);
#pragma unroll
                for (int mt = 0; mt < 4; ++mt)
                    acc3[nt][mt] = __builtin_amdgcn_mfma_f32_16x16x32_bf16(a[mt], b, acc3[nt][mt], 0, 0, 0);
            }
        }
    }
    // ---- h2 = ReLU(acc3 + b2) -> sF overlay (all sF reads completed before phase-1 barrier)
    {
#pragma unroll
        for (int nt = 0; nt < 2; ++nt) {
            int ncol = w * 32 + nt * 16 + ln;   // 0..255
            float bv = b2[ncol];
            int cch = ncol >> 3, coff = ncol & 7;
#pragma unroll
            for (int mt = 0; mt < 4; ++mt)
#pragma unroll
                for (int i = 0; i < 4; ++i) {
                    int row = mt * 16 + lq * 4 + i;
                    sF[SFCH(row, cch) * 8 + coff] = f2b(fmaxf(acc3[nt][mt][i] + bv, 0.0f));
                }
        }
    }
    __syncthreads();
    // ---- layer 3: out = h2 @ W3^T + b3
    {
        int r = tid >> 3, p = tid & 7;   // 64 rows x 8 threads (32 cols each)
        float sum = 0.0f;
#pragma unroll
        for (int j = 0; j < 4; ++j) {
            int c = p + j * 8;
            const unsigned short* hp = sF + SFCH(r, c) * 8;
            const float* w3p = W3 + c * 8;
#pragma unroll
            for (int e = 0; e < 8; ++e) sum += b2f(hp[e]) * w3p[e];
        }
        sum += __shfl_down(sum, 4, 8);
        sum += __shfl_down(sum, 2, 8);
        sum += __shfl_down(sum, 1, 8);
        if (p == 0 && row0 + r < NL) out[row0 + r] = sum + b3[0];
    }
}

// ---------------------------------------------------------------- host
extern "C" void kernel_launch(void* const* d_in, const int* in_sizes, int n_in,
                              void* d_out, int out_size, void* d_ws, size_t ws_size,
                              hipStream_t stream) {
    const float* x_user  = (const float*)d_in[0];
    const float* x_movie = (const float*)d_in[1];
    const int*   ei      = (const int*)d_in[2];
    const int*   eli     = (const int*)d_in[3];
    const float* lin_u_W = (const float*)d_in[4];
    const float* lin_u_b = (const float*)d_in[5];
    const float* lin_m_W = (const float*)d_in[6];
    const float* lin_m_b = (const float*)d_in[7];
    const float* bn_u_g  = (const float*)d_in[8];
    const float* bn_u_b  = (const float*)d_in[9];
    const float* bn_u_m  = (const float*)d_in[10];
    const float* bn_u_v  = (const float*)d_in[11];
    const float* bn_m_g  = (const float*)d_in[12];
    const float* bn_m_b  = (const float*)d_in[13];
    const float* bn_m_m  = (const float*)d_in[14];
    const float* bn_m_v  = (const float*)d_in[15];
    const float* c1_um_Wl = (const float*)d_in[16];
    const float* c1_um_bl = (const float*)d_in[17];
    const float* c1_um_Wr = (const float*)d_in[18];
    const float* c1_mu_Wl = (const float*)d_in[19];
    const float* c1_mu_bl = (const float*)d_in[20];
    const float* c1_mu_Wr = (const float*)d_in[21];
    const float* c2_um_Wl = (const float*)d_in[22];
    const float* c2_um_bl = (const float*)d_in[23];
    const float* c2_um_Wr = (const float*)d_in[24];
    const float* c2_mu_Wl = (const float*)d_in[25];
    const float* c2_mu_bl = (const float*)d_in[26];
    const float* c2_mu_Wr = (const float*)d_in[27];
    const float* dec_W1 = (const float*)d_in[28];
    const float* dec_b1 = (const float*)d_in[29];
    const float* dec_W2 = (const float*)d_in[30];
    const float* dec_b2 = (const float*)d_in[31];
    const float* dec_W3 = (const float*)d_in[32];
    const float* dec_b3 = (const float*)d_in[33];

    char* base = (char*)d_ws;
    size_t off = 0;
    auto alloc = [&](size_t bytes) -> char* {
        char* p = base + off;
        off += (bytes + 255) & ~(size_t)255;
        return p;
    };
    unsigned short* xu_b  = (unsigned short*)alloc((size_t)NU * H * 2);
    unsigned short* xm_b  = (unsigned short*)alloc((size_t)NM * H * 2);
    unsigned short* xu1_b = (unsigned short*)alloc((size_t)NU * H * 2);
    unsigned short* xm1_b = (unsigned short*)alloc((size_t)NM * H * 2);
    unsigned short* aggu  = (unsigned short*)alloc((size_t)NU * H * 2);
    unsigned short* aggm  = (unsigned short*)alloc((size_t)NM * H * 2);
    float* wt_u = (float*)alloc((size_t)64 * H * 4);
    float* wt_m = (float*)alloc((size_t)H * H * 4);
    unsigned short* wsg = (unsigned short*)alloc((size_t)8 * 16384 * 2);  // packed sage weights
    unsigned short* w1p = (unsigned short*)alloc((size_t)512 * 256 * 2);
    unsigned short* w2p = (unsigned short*)alloc((size_t)256 * 512 * 2);
    int* rp_m  = (int*)alloc((size_t)(NM + 1) * 4);
    int* rp_u  = (int*)alloc((size_t)(NU + 1) * 4);
    int* cur_m = (int*)alloc((size_t)NM * 4);
    int* cur_u = (int*)alloc((size_t)NU * 4);
    int* es_m  = (int*)alloc((size_t)NE * 4);
    int* es_u  = (int*)alloc((size_t)NE * 4);
    unsigned short* zu = xu_b;   // xu_b dead after conv1 sage -> reuse
    unsigned short* zm = xm_b;

    // zero CSR meta (rp_m .. cur_u incl. padding)
    hipMemsetAsync(rp_m, 0, (size_t)((char*)es_m - (char*)rp_m), stream);

    TPack tp;
    tp.t[0] = { lin_u_W, wt_u, H, 64 };
    tp.t[1] = { lin_m_W, wt_m, H, H };
    transpose_all<<<dim3(64, 2), 256, 0, stream>>>(tp);
    pack_weights<<<256, 256, 0, stream>>>(dec_W1, dec_W2, w1p, w2p);
    SPack sp;
    sp.w[0] = c1_um_Wl; sp.w[1] = c1_um_Wr; sp.w[2] = c1_mu_Wl; sp.w[3] = c1_mu_Wr;
    sp.w[4] = c2_um_Wl; sp.w[5] = c2_um_Wr; sp.w[6] = c2_mu_Wl; sp.w[7] = c2_mu_Wr;
    pack_sage<<<128, 256, 0, stream>>>(sp, wsg);
    const unsigned short* W_c1um_l = wsg + 0 * 16384;
    const unsigned short* W_c1um_r = wsg + 1 * 16384;
    const unsigned short* W_c1mu_l = wsg + 2 * 16384;
    const unsigned short* W_c1mu_r = wsg + 3 * 16384;
    const unsigned short* W_c2um_l = wsg + 4 * 16384;
    const unsigned short* W_c2um_r = wsg + 5 * 16384;
    const unsigned short* W_c2mu_l = wsg + 6 * 16384;
    const unsigned short* W_c2mu_r = wsg + 7 * 16384;

    deg_kernel<<<2048, 256, 0, stream>>>(ei, rp_m, rp_u);
    scan2_kernel<<<2, 256, 0, stream>>>(rp_m, NM + 1, rp_u, NU + 1);
    bucket_kernel<<<2048, 256, 0, stream>>>(ei, rp_m, rp_u, cur_m, cur_u, es_m, es_u);

    proj_kernel<64><<<(NU + 63) / 64, 256, 0, stream>>>(
        x_user, wt_u, lin_u_b, bn_u_g, bn_u_b, bn_u_m, bn_u_v, xu_b, NU);
    proj_kernel<128><<<(NM + 63) / 64, 256, 0, stream>>>(
        x_movie, wt_m, lin_m_b, bn_m_g, bn_m_b, bn_m_m, bn_m_v, xm_b, NM);

    const int AGG_BLOCKS = (NM + NU + 3) / 4;
    const int NBLK_M = (NM + 63) / 64, NBLK_U = (NU + 63) / 64;

    // conv1
    agg_bf16<<<AGG_BLOCKS, 256, 0, stream>>>(xu_b, es_m, rp_m, aggm, NM,
                                             xm_b, es_u, rp_u, aggu, NU);
    sage_mfma<<<NBLK_M + NBLK_U, 256, 0, stream>>>(
        aggm, xm_b, W_c1um_l, W_c1um_r, c1_um_bl, xm1_b, NM, NBLK_M,
        aggu, xu_b, W_c1mu_l, W_c1mu_r, c1_mu_bl, xu1_b, NU, 1);
    // conv2
    agg_bf16<<<AGG_BLOCKS, 256, 0, stream>>>(xu1_b, es_m, rp_m, aggm, NM,
                                             xm1_b, es_u, rp_u, aggu, NU);
    sage_mfma<<<NBLK_M + NBLK_U, 256, 0, stream>>>(
        aggm, xm1_b, W_c2um_l, W_c2um_r, c2_um_bl, zm, NM, NBLK_M,
        aggu, xu1_b, W_c2mu_l, W_c2mu_r, c2_mu_bl, zu, NU, 0);

    // decoder (bf16 MFMA, 3-phase nt=4, 96 KB LDS, 256 regs/wave)
    decoder_mfma<<<(NL + 63) / 64, 512, 0, stream>>>(
        zu, zm, eli, w1p, dec_b1, w2p, dec_b2, dec_W3, dec_b3, (float*)d_out);
}

// Round 11
// 1290.242 us; speedup vs baseline: 1.1048x; 1.0194x over previous
//
#include <hip/hip_runtime.h>

#define NU 100000
#define NM 20000
#define NE 2000000
#define NL 500000
#define H  128

typedef __attribute__((ext_vector_type(8))) short bf16x8;            // 8 bf16 (4 VGPRs)
typedef __attribute__((ext_vector_type(4))) float floatx4;           // 4 fp32 acc
typedef __attribute__((ext_vector_type(8))) unsigned short u16x8;    // 16B load/store
typedef __attribute__((ext_vector_type(4))) unsigned short u16x4;    // 8B store

__device__ __forceinline__ unsigned short f2b(float x) {
    union { float f; unsigned u; } v; v.f = x;
    unsigned r = v.u + 0x7FFFu + ((v.u >> 16) & 1u);  // RNE
    return (unsigned short)(r >> 16);
}
__device__ __forceinline__ float b2f(unsigned short h) {
    union { unsigned u; float f; } v; v.u = ((unsigned)h) << 16;
    return v.f;
}
__device__ __forceinline__ float b2f_lo(unsigned v) {  // low ushort of packed pair
    union { unsigned u; float f; } t; t.u = v << 16; return t.f;
}
__device__ __forceinline__ float b2f_hi(unsigned v) {
    union { unsigned u; float f; } t; t.u = v & 0xFFFF0000u; return t.f;
}

// rotated LDS chunk addressing (chunk = 16B = 8 bf16), zero-waste bank pad.
#define SFCH(r, c)  ((r) * 32 + (((c) + (r)) & 31))   // 64 rows x 32 chunks (256 cols)
#define SH1CH(r, c) ((r) * 16 + (((c) + (r)) & 15))   // 64 rows x 16 chunks (128 cols)
#define SH2CH(r, c) ((r) * 64 + (((c) + (r)) & 63))   // 64 rows x 64 chunks (512 cols)

// ---------------------------------------------------------------- transpose (proj weights only)
struct TDesc { const float* s; float* d; int R; int C; };
struct TPack { TDesc t[2]; };

__global__ __launch_bounds__(256) void transpose_all(TPack p) {
    TDesc d = p.t[blockIdx.y];
    int n = d.R * d.C;
    for (int i = blockIdx.x * 256 + threadIdx.x; i < n; i += gridDim.x * 256) {
        int r = i / d.C, c = i - r * d.C;
        d.d[c * d.R + r] = d.s[i];  // dst[k][h] = src[h][k]
    }
}

// ---------------------------------------------------------------- pack decoder weights into MFMA frag order
// (A-fragment and B-fragment lane layouts are identical for 16x16x32)
__global__ __launch_bounds__(256) void pack_weights(const float* __restrict__ W1,
                                                    const float* __restrict__ W2,
                                                    unsigned short* __restrict__ W1p,
                                                    unsigned short* __restrict__ W2p) {
    const int n = 512 * 256;
    for (int i = blockIdx.x * 256 + threadIdx.x; i < n; i += gridDim.x * 256) {
        int j = i & 7, lane = (i >> 3) & 63;
        int ln = lane & 15, lq = lane >> 4;
        int kg1 = (i >> 9) & 7,  t1 = i >> 12;
        W1p[i] = f2b(W1[(t1 * 16 + ln) * 256 + kg1 * 32 + lq * 8 + j]);
        int kg2 = (i >> 9) & 15, t2 = i >> 13;
        W2p[i] = f2b(W2[(t2 * 16 + ln) * 512 + kg2 * 32 + lq * 8 + j]);
    }
}

// ---------------------------------------------------------------- pack 8 sage weights (H x H) into B-frag order
struct SPack { const float* w[8]; };
__global__ __launch_bounds__(256) void pack_sage(SPack sp, unsigned short* __restrict__ out) {
    const int n = 8 * 16384;
    for (int i = blockIdx.x * 256 + threadIdx.x; i < n; i += gridDim.x * 256) {
        int j = i & 7, lane = (i >> 3) & 63;
        int kg = (i >> 9) & 3, t = (i >> 11) & 7, wsel = i >> 14;
        int ln = lane & 15, lq = lane >> 4;
        out[i] = f2b(sp.w[wsel][(t * 16 + ln) * H + kg * 32 + lq * 8 + j]);
    }
}

// ---------------------------------------------------------------- CSR build
__global__ __launch_bounds__(256) void deg_kernel(const int* __restrict__ ei,
                                                  int* rp_m, int* rp_u) {
    for (int i = blockIdx.x * 256 + threadIdx.x; i < NE; i += gridDim.x * 256) {
        int u = ei[i], m = ei[NE + i];
        atomicAdd(&rp_u[u + 1], 1);
        atomicAdd(&rp_m[m + 1], 1);
    }
}

__global__ __launch_bounds__(256) void scan2_kernel(int* rp_m, int n_m,
                                                    int* rp_u, int n_u) {
    int* a = (blockIdx.x == 0) ? rp_m : rp_u;
    int n  = (blockIdx.x == 0) ? n_m : n_u;
    __shared__ int s[256];
    __shared__ int carry;
    int tid = threadIdx.x;
    if (tid == 0) carry = 0;
    __syncthreads();
    for (int base = 0; base < n; base += 4096) {
        int v[16];
        int run = 0;
        int i0 = base + tid * 16;
#pragma unroll
        for (int i = 0; i < 16; ++i) {
            int x = (i0 + i < n) ? a[i0 + i] : 0;
            run += x; v[i] = run;
        }
        s[tid] = run;
        __syncthreads();
        for (int off = 1; off < 256; off <<= 1) {
            int t = (tid >= off) ? s[tid - off] : 0;
            __syncthreads();
            s[tid] += t;
            __syncthreads();
        }
        int prev = carry + (tid > 0 ? s[tid - 1] : 0);
#pragma unroll
        for (int i = 0; i < 16; ++i)
            if (i0 + i < n) a[i0 + i] = v[i] + prev;
        int total = s[255];
        __syncthreads();
        if (tid == 0) carry += total;
        __syncthreads();
    }
}

__global__ __launch_bounds__(256) void bucket_kernel(const int* __restrict__ ei,
        const int* __restrict__ rp_m, const int* __restrict__ rp_u,
        int* cur_m, int* cur_u, int* es_m, int* es_u) {
    for (int i = blockIdx.x * 256 + threadIdx.x; i < NE; i += gridDim.x * 256) {
        int u = ei[i], m = ei[NE + i];
        int pm = atomicAdd(&cur_m[m], 1);
        es_m[rp_m[m] + pm] = u;
        int pu = atomicAdd(&cur_u[u], 1);
        es_u[rp_u[u] + pu] = m;
    }
}

// ---------------------------------------------------------------- projection (Linear + BN(eval) + ReLU) -> bf16
template <int K>
__global__ __launch_bounds__(256, 2) void proj_kernel(
        const float* __restrict__ x, const float* __restrict__ Wt,
        const float* __restrict__ lb, const float* __restrict__ g,
        const float* __restrict__ bb, const float* __restrict__ bm,
        const float* __restrict__ bv, unsigned short* __restrict__ out, int N) {
    __shared__ float sA[64 * K];
    const int tid = threadIdx.x;
    const int row0 = blockIdx.x * 64;
    constexpr int F4 = K / 4;
#pragma unroll
    for (int i = 0; i < (64 * F4) / 256; ++i) {
        int idx = tid + i * 256;
        int r = idx / F4, c = idx - r * F4;
        int gr = min(row0 + r, N - 1);
        ((float4*)sA)[idx] = ((const float4*)(x + (size_t)gr * K))[c];
    }
    __syncthreads();
    const int h_t = tid & 31, r_t = tid >> 5;
    float acc[8][4] = {};
#pragma unroll 4
    for (int k = 0; k < K; k += 4) {
        float4 w[4];
#pragma unroll
        for (int kk = 0; kk < 4; ++kk)
            w[kk] = *(const float4*)(Wt + (k + kk) * H + h_t * 4);
#pragma unroll
        for (int rr = 0; rr < 8; ++rr) {
            float4 a = *(const float4*)(sA + (r_t * 8 + rr) * K + k);
            acc[rr][0] += a.x * w[0].x + a.y * w[1].x + a.z * w[2].x + a.w * w[3].x;
            acc[rr][1] += a.x * w[0].y + a.y * w[1].y + a.z * w[2].y + a.w * w[3].y;
            acc[rr][2] += a.x * w[0].z + a.y * w[1].z + a.z * w[2].z + a.w * w[3].z;
            acc[rr][3] += a.x * w[0].w + a.y * w[1].w + a.z * w[2].w + a.w * w[3].w;
        }
    }
    const int h = h_t * 4;
    float4 lb4 = *(const float4*)(lb + h);
    float4 g4  = *(const float4*)(g  + h);
    float4 bb4 = *(const float4*)(bb + h);
    float4 m4  = *(const float4*)(bm + h);
    float4 v4  = *(const float4*)(bv + h);
    float sc[4] = { g4.x * rsqrtf(v4.x + 1e-5f), g4.y * rsqrtf(v4.y + 1e-5f),
                    g4.z * rsqrtf(v4.z + 1e-5f), g4.w * rsqrtf(v4.w + 1e-5f) };
    float lbv[4] = { lb4.x, lb4.y, lb4.z, lb4.w };
    float mv[4]  = { m4.x, m4.y, m4.z, m4.w };
    float bbv[4] = { bb4.x, bb4.y, bb4.z, bb4.w };
#pragma unroll
    for (int rr = 0; rr < 8; ++rr) {
        int gr = row0 + r_t * 8 + rr;
        if (gr < N) {
            u16x4 o;
#pragma unroll
            for (int c = 0; c < 4; ++c)
                o[c] = f2b(fmaxf((acc[rr][c] + lbv[c] - mv[c]) * sc[c] + bbv[c], 0.0f));
            *(u16x4*)(out + (size_t)gr * H + h) = o;
        }
    }
}

// ---------------------------------------------------------------- segment mean (bf16 in/out, fp32 acc)
// one WAVE per node; 8 row-loads in flight (latency-bound gather).
__global__ __launch_bounds__(256) void agg_bf16(
        const unsigned short* __restrict__ srcA, const int* __restrict__ esA,
        const int* __restrict__ rpA, unsigned short* __restrict__ outA, int nA,
        const unsigned short* __restrict__ srcB, const int* __restrict__ esB,
        const int* __restrict__ rpB, unsigned short* __restrict__ outB, int nB) {
    int wid = blockIdx.x * 4 + (threadIdx.x >> 6);
    const int lane = threadIdx.x & 63;
    const unsigned short* src; const int* es; const int* rp; unsigned short* out; int n;
    if (wid < nA) { src = srcA; es = esA; rp = rpA; out = outA; n = wid; }
    else {
        wid -= nA;
        if (wid >= nB) return;
        src = srcB; es = esB; rp = rpB; out = outB; n = wid;
    }
    const int start = rp[n], end = rp[n + 1];
    float a0 = 0.0f, a1 = 0.0f;
    int j = start;
    for (; j + 8 <= end; j += 8) {
        unsigned v[8];
#pragma unroll
        for (int q = 0; q < 8; ++q)
            v[q] = *(const unsigned*)(src + (size_t)es[j + q] * H + lane * 2);
#pragma unroll
        for (int q = 0; q < 8; ++q) { a0 += b2f_lo(v[q]); a1 += b2f_hi(v[q]); }
    }
    for (; j < end; ++j) {
        unsigned v = *(const unsigned*)(src + (size_t)es[j] * H + lane * 2);
        a0 += b2f_lo(v); a1 += b2f_hi(v);
    }
    float inv = (end > start) ? 1.0f / (float)(end - start) : 0.0f;
    unsigned o = (unsigned)f2b(a0 * inv) | ((unsigned)f2b(a1 * inv) << 16);
    *(unsigned*)(out + (size_t)n * H + lane * 2) = o;
}

// ---------------------------------------------------------------- SAGE via MFMA
__global__ __launch_bounds__(256, 4) void sage_mfma(
        const unsigned short* __restrict__ aggA, const unsigned short* __restrict__ xA,
        const unsigned short* __restrict__ WlA, const unsigned short* __restrict__ WrA,
        const float* __restrict__ blA, unsigned short* __restrict__ outA, int NA, int NBLKA,
        const unsigned short* __restrict__ aggB, const unsigned short* __restrict__ xB,
        const unsigned short* __restrict__ WlB, const unsigned short* __restrict__ WrB,
        const float* __restrict__ blB, unsigned short* __restrict__ outB, int NB,
        int relu) {
    __shared__ unsigned short sAg[64 * 16 * 8];  // 16 KB
    __shared__ unsigned short sX[64 * 16 * 8];   // 16 KB
    const int tid = threadIdx.x;
    const unsigned short *agg, *x, *Wl, *Wr; const float* bl; unsigned short* out;
    int N, row0;
    if ((int)blockIdx.x < NBLKA) {
        agg = aggA; x = xA; Wl = WlA; Wr = WrA; bl = blA; out = outA; N = NA;
        row0 = blockIdx.x * 64;
    } else {
        agg = aggB; x = xB; Wl = WlB; Wr = WrB; bl = blB; out = outB; N = NB;
        row0 = (blockIdx.x - NBLKA) * 64;
    }
#pragma unroll
    for (int i = 0; i < 4; ++i) {
        int idx = tid + i * 256;           // 1024 chunks
        int r = idx >> 4, c = idx & 15;
        int gr = min(row0 + r, N - 1);
        *(u16x8*)(sAg + SH1CH(r, c) * 8) = *(const u16x8*)(agg + (size_t)gr * H + c * 8);
        *(u16x8*)(sX  + SH1CH(r, c) * 8) = *(const u16x8*)(x   + (size_t)gr * H + c * 8);
    }
    __syncthreads();
    const int lane = tid & 63, w = tid >> 6;
    const int ln = lane & 15, lq = lane >> 4;
    floatx4 acc[2][4] = {};
#pragma unroll 2
    for (int kg = 0; kg < 4; ++kg) {
        bf16x8 aA[4], aX[4];
#pragma unroll
        for (int mt = 0; mt < 4; ++mt) {
            aA[mt] = *(const bf16x8*)(sAg + SH1CH(mt * 16 + ln, kg * 4 + lq) * 8);
            aX[mt] = *(const bf16x8*)(sX  + SH1CH(mt * 16 + ln, kg * 4 + lq) * 8);
        }
#pragma unroll
        for (int nt = 0; nt < 2; ++nt) {
            int widx = ((w * 2 + nt) * 4 + kg) * 512 + lane * 8;
            bf16x8 bL = *(const bf16x8*)(Wl + widx);
            bf16x8 bR = *(const bf16x8*)(Wr + widx);
#pragma unroll
            for (int mt = 0; mt < 4; ++mt) {
                acc[nt][mt] = __builtin_amdgcn_mfma_f32_16x16x32_bf16(aA[mt], bL, acc[nt][mt], 0, 0, 0);
                acc[nt][mt] = __builtin_amdgcn_mfma_f32_16x16x32_bf16(aX[mt], bR, acc[nt][mt], 0, 0, 0);
            }
        }
    }
    __syncthreads();   // done reading sAg; reuse it for output staging
    {
#pragma unroll
        for (int nt = 0; nt < 2; ++nt) {
            int ncol = w * 32 + nt * 16 + ln;   // 0..127
            float bv = bl[ncol];
            int cch = ncol >> 3, coff = ncol & 7;
#pragma unroll
            for (int mt = 0; mt < 4; ++mt)
#pragma unroll
                for (int i = 0; i < 4; ++i) {
                    int row = mt * 16 + lq * 4 + i;
                    float v = acc[nt][mt][i] + bv;
                    if (relu) v = fmaxf(v, 0.0f);
                    sAg[SH1CH(row, cch) * 8 + coff] = f2b(v);
                }
        }
    }
    __syncthreads();
#pragma unroll
    for (int i = 0; i < 4; ++i) {
        int idx = tid + i * 256;
        int r = idx >> 4, c = idx & 15;
        int gr = row0 + r;
        if (gr < N)
            *(u16x8*)(out + (size_t)gr * H + c * 8) = *(const u16x8*)(sAg + SH1CH(r, c) * 8);
    }
}

// ---------------------------------------------------------------- fused edge decoder MLP — 3-phase, SWAPPED operands
// MFMA A-frag and B-frag lane layouts are identical (16x16x32), so computing
// D = W · feat^T (weights as A, activations as B) makes the C-layout
// (col = lane&15 = edge row; regs = 4 consecutive out-cols) line up with the
// row-major LDS h1/h2 buffers: each (nt,mt) epilogue store is ONE ds_write_b64
// instead of 4 scalar ds_write_u16 (R10: 96 scalar stores/thread -> 24 b64).
// Fragment reads and W1p/W2p packing unchanged. 96 KB LDS, (512,2): 256 regs/wave.
__global__ __launch_bounds__(512, 2) void decoder_mfma(
        const unsigned short* __restrict__ zu, const unsigned short* __restrict__ zm,
        const int* __restrict__ eli,
        const unsigned short* __restrict__ W1p, const float* __restrict__ b1,
        const unsigned short* __restrict__ W2p, const float* __restrict__ b2,
        const float* __restrict__ W3, const float* __restrict__ b3,
        float* __restrict__ out) {
    __shared__ unsigned short sF[64 * 32 * 8];   // feat 64x256 bf16 rotated (32 KB), later h2
    __shared__ unsigned short sH1[64 * 64 * 8];  // h1 FULL 64x512 bf16 rotated (64 KB)
    const int tid = threadIdx.x;
    const int row0 = blockIdx.x * 64;
    // ---- gather feat = [zu[eu] | zm[em]] (bf16 straight copy)
    {
        int r = tid >> 3, p = tid & 7;
        int rg = min(row0 + r, NL - 1);
        int iu = eli[rg], im = eli[NL + rg];
        const unsigned short* zur = zu + (size_t)iu * H;
        const unsigned short* zmr = zm + (size_t)im * H;
#pragma unroll
        for (int j = 0; j < 4; ++j) {
            int c = p + j * 8;   // 0..31
            const unsigned short* s = (c < 16) ? (zur + c * 8) : (zmr + (c - 16) * 8);
            *(u16x8*)(sF + SFCH(r, c) * 8) = *(const u16x8*)s;
        }
    }
    __syncthreads();
    const int lane = tid & 63, w = tid >> 6;   // 8 waves
    const int ln = lane & 15, lq = lane >> 4;
    // ---- phase 1: h1^T = W1 · feat^T ; wave w owns h1 cols [w*64, +64)
    {
        floatx4 acc1[4][4] = {};   // [nt: h1col tile][mt: edge-row tile]
        const unsigned short* w1base = W1p + ((size_t)(w * 4) * 8) * 512 + lane * 8;
#pragma unroll 2
        for (int kg = 0; kg < 8; ++kg) {
            bf16x8 fb[4];   // feat fragments (B operand): B[n=edge row][k]
#pragma unroll
            for (int mt = 0; mt < 4; ++mt)
                fb[mt] = *(const bf16x8*)(sF + SFCH(mt * 16 + ln, kg * 4 + lq) * 8);
#pragma unroll
            for (int nt = 0; nt < 4; ++nt) {
                bf16x8 wa = *(const bf16x8*)(w1base + (size_t)(nt * 8 + kg) * 512);  // A: W1 rows
#pragma unroll
                for (int mt = 0; mt < 4; ++mt)
                    acc1[nt][mt] = __builtin_amdgcn_mfma_f32_16x16x32_bf16(wa, fb[mt], acc1[nt][mt], 0, 0, 0);
            }
        }
        // epilogue: D[row=h1col lq*4+i][col=edge row ln] -> b64 store per (nt,mt)
#pragma unroll
        for (int nt = 0; nt < 4; ++nt) {
            int colbase = w * 64 + nt * 16 + lq * 4;   // h1 col of reg 0
            float4 bv = *(const float4*)(b1 + colbase);
            int cch = colbase >> 3, coff = colbase & 7;   // coff = (lq&1)*4
#pragma unroll
            for (int mt = 0; mt < 4; ++mt) {
                int erow = mt * 16 + ln;
                u16x4 o = { f2b(fmaxf(acc1[nt][mt][0] + bv.x, 0.0f)),
                            f2b(fmaxf(acc1[nt][mt][1] + bv.y, 0.0f)),
                            f2b(fmaxf(acc1[nt][mt][2] + bv.z, 0.0f)),
                            f2b(fmaxf(acc1[nt][mt][3] + bv.w, 0.0f)) };
                *(u16x4*)(sH1 + SH2CH(erow, cch) * 8 + coff) = o;
            }
        }
    }
    __syncthreads();
    // ---- phase 2: h2^T = W2 · h1^T over full K=512; wave w owns h2 cols [w*32,+32)
    floatx4 acc3[2][4] = {};
    {
        const unsigned short* w2base = W2p + ((size_t)(w * 2) * 16) * 512 + lane * 8;
#pragma unroll 2
        for (int kg = 0; kg < 16; ++kg) {
            bf16x8 hb[4];   // h1 fragments (B operand)
#pragma unroll
            for (int mt = 0; mt < 4; ++mt)
                hb[mt] = *(const bf16x8*)(sH1 + SH2CH(mt * 16 + ln, kg * 4 + lq) * 8);
#pragma unroll
            for (int nt = 0; nt < 2; ++nt) {
                bf16x8 wa = *(const bf16x8*)(w2base + (size_t)(nt * 16 + kg) * 512);
#pragma unroll
                for (int mt = 0; mt < 4; ++mt)
                    acc3[nt][mt] = __builtin_amdgcn_mfma_f32_16x16x32_bf16(wa, hb[mt], acc3[nt][mt], 0, 0, 0);
            }
        }
    }
    // ---- h2 = ReLU(acc3 + b2) -> sF overlay, b64 stores
    {
#pragma unroll
        for (int nt = 0; nt < 2; ++nt) {
            int colbase = w * 32 + nt * 16 + lq * 4;   // h2 col of reg 0
            float4 bv = *(const float4*)(b2 + colbase);
            int cch = colbase >> 3, coff = colbase & 7;
#pragma unroll
            for (int mt = 0; mt < 4; ++mt) {
                int erow = mt * 16 + ln;
                u16x4 o = { f2b(fmaxf(acc3[nt][mt][0] + bv.x, 0.0f)),
                            f2b(fmaxf(acc3[nt][mt][1] + bv.y, 0.0f)),
                            f2b(fmaxf(acc3[nt][mt][2] + bv.z, 0.0f)),
                            f2b(fmaxf(acc3[nt][mt][3] + bv.w, 0.0f)) };
                *(u16x4*)(sF + SFCH(erow, cch) * 8 + coff) = o;
            }
        }
    }
    __syncthreads();
    // ---- layer 3: out = h2 @ W3^T + b3
    {
        int r = tid >> 3, p = tid & 7;   // 64 rows x 8 threads (32 cols each)
        float sum = 0.0f;
#pragma unroll
        for (int j = 0; j < 4; ++j) {
            int c = p + j * 8;
            const unsigned short* hp = sF + SFCH(r, c) * 8;
            const float* w3p = W3 + c * 8;
#pragma unroll
            for (int e = 0; e < 8; ++e) sum += b2f(hp[e]) * w3p[e];
        }
        sum += __shfl_down(sum, 4, 8);
        sum += __shfl_down(sum, 2, 8);
        sum += __shfl_down(sum, 1, 8);
        if (p == 0 && row0 + r < NL) out[row0 + r] = sum + b3[0];
    }
}

// ---------------------------------------------------------------- host
extern "C" void kernel_launch(void* const* d_in, const int* in_sizes, int n_in,
                              void* d_out, int out_size, void* d_ws, size_t ws_size,
                              hipStream_t stream) {
    const float* x_user  = (const float*)d_in[0];
    const float* x_movie = (const float*)d_in[1];
    const int*   ei      = (const int*)d_in[2];
    const int*   eli     = (const int*)d_in[3];
    const float* lin_u_W = (const float*)d_in[4];
    const float* lin_u_b = (const float*)d_in[5];
    const float* lin_m_W = (const float*)d_in[6];
    const float* lin_m_b = (const float*)d_in[7];
    const float* bn_u_g  = (const float*)d_in[8];
    const float* bn_u_b  = (const float*)d_in[9];
    const float* bn_u_m  = (const float*)d_in[10];
    const float* bn_u_v  = (const float*)d_in[11];
    const float* bn_m_g  = (const float*)d_in[12];
    const float* bn_m_b  = (const float*)d_in[13];
    const float* bn_m_m  = (const float*)d_in[14];
    const float* bn_m_v  = (const float*)d_in[15];
    const float* c1_um_Wl = (const float*)d_in[16];
    const float* c1_um_bl = (const float*)d_in[17];
    const float* c1_um_Wr = (const float*)d_in[18];
    const float* c1_mu_Wl = (const float*)d_in[19];
    const float* c1_mu_bl = (const float*)d_in[20];
    const float* c1_mu_Wr = (const float*)d_in[21];
    const float* c2_um_Wl = (const float*)d_in[22];
    const float* c2_um_bl = (const float*)d_in[23];
    const float* c2_um_Wr = (const float*)d_in[24];
    const float* c2_mu_Wl = (const float*)d_in[25];
    const float* c2_mu_bl = (const float*)d_in[26];
    const float* c2_mu_Wr = (const float*)d_in[27];
    const float* dec_W1 = (const float*)d_in[28];
    const float* dec_b1 = (const float*)d_in[29];
    const float* dec_W2 = (const float*)d_in[30];
    const float* dec_b2 = (const float*)d_in[31];
    const float* dec_W3 = (const float*)d_in[32];
    const float* dec_b3 = (const float*)d_in[33];

    char* base = (char*)d_ws;
    size_t off = 0;
    auto alloc = [&](size_t bytes) -> char* {
        char* p = base + off;
        off += (bytes + 255) & ~(size_t)255;
        return p;
    };
    unsigned short* xu_b  = (unsigned short*)alloc((size_t)NU * H * 2);
    unsigned short* xm_b  = (unsigned short*)alloc((size_t)NM * H * 2);
    unsigned short* xu1_b = (unsigned short*)alloc((size_t)NU * H * 2);
    unsigned short* xm1_b = (unsigned short*)alloc((size_t)NM * H * 2);
    unsigned short* aggu  = (unsigned short*)alloc((size_t)NU * H * 2);
    unsigned short* aggm  = (unsigned short*)alloc((size_t)NM * H * 2);
    float* wt_u = (float*)alloc((size_t)64 * H * 4);
    float* wt_m = (float*)alloc((size_t)H * H * 4);
    unsigned short* wsg = (unsigned short*)alloc((size_t)8 * 16384 * 2);  // packed sage weights
    unsigned short* w1p = (unsigned short*)alloc((size_t)512 * 256 * 2);
    unsigned short* w2p = (unsigned short*)alloc((size_t)256 * 512 * 2);
    int* rp_m  = (int*)alloc((size_t)(NM + 1) * 4);
    int* rp_u  = (int*)alloc((size_t)(NU + 1) * 4);
    int* cur_m = (int*)alloc((size_t)NM * 4);
    int* cur_u = (int*)alloc((size_t)NU * 4);
    int* es_m  = (int*)alloc((size_t)NE * 4);
    int* es_u  = (int*)alloc((size_t)NE * 4);
    unsigned short* zu = xu_b;   // xu_b dead after conv1 sage -> reuse
    unsigned short* zm = xm_b;

    // zero CSR meta (rp_m .. cur_u incl. padding)
    hipMemsetAsync(rp_m, 0, (size_t)((char*)es_m - (char*)rp_m), stream);

    TPack tp;
    tp.t[0] = { lin_u_W, wt_u, H, 64 };
    tp.t[1] = { lin_m_W, wt_m, H, H };
    transpose_all<<<dim3(64, 2), 256, 0, stream>>>(tp);
    pack_weights<<<256, 256, 0, stream>>>(dec_W1, dec_W2, w1p, w2p);
    SPack sp;
    sp.w[0] = c1_um_Wl; sp.w[1] = c1_um_Wr; sp.w[2] = c1_mu_Wl; sp.w[3] = c1_mu_Wr;
    sp.w[4] = c2_um_Wl; sp.w[5] = c2_um_Wr; sp.w[6] = c2_mu_Wl; sp.w[7] = c2_mu_Wr;
    pack_sage<<<128, 256, 0, stream>>>(sp, wsg);
    const unsigned short* W_c1um_l = wsg + 0 * 16384;
    const unsigned short* W_c1um_r = wsg + 1 * 16384;
    const unsigned short* W_c1mu_l = wsg + 2 * 16384;
    const unsigned short* W_c1mu_r = wsg + 3 * 16384;
    const unsigned short* W_c2um_l = wsg + 4 * 16384;
    const unsigned short* W_c2um_r = wsg + 5 * 16384;
    const unsigned short* W_c2mu_l = wsg + 6 * 16384;
    const unsigned short* W_c2mu_r = wsg + 7 * 16384;

    deg_kernel<<<2048, 256, 0, stream>>>(ei, rp_m, rp_u);
    scan2_kernel<<<2, 256, 0, stream>>>(rp_m, NM + 1, rp_u, NU + 1);
    bucket_kernel<<<2048, 256, 0, stream>>>(ei, rp_m, rp_u, cur_m, cur_u, es_m, es_u);

    proj_kernel<64><<<(NU + 63) / 64, 256, 0, stream>>>(
        x_user, wt_u, lin_u_b, bn_u_g, bn_u_b, bn_u_m, bn_u_v, xu_b, NU);
    proj_kernel<128><<<(NM + 63) / 64, 256, 0, stream>>>(
        x_movie, wt_m, lin_m_b, bn_m_g, bn_m_b, bn_m_m, bn_m_v, xm_b, NM);

    const int AGG_BLOCKS = (NM + NU + 3) / 4;
    const int NBLK_M = (NM + 63) / 64, NBLK_U = (NU + 63) / 64;

    // conv1
    agg_bf16<<<AGG_BLOCKS, 256, 0, stream>>>(xu_b, es_m, rp_m, aggm, NM,
                                             xm_b, es_u, rp_u, aggu, NU);
    sage_mfma<<<NBLK_M + NBLK_U, 256, 0, stream>>>(
        aggm, xm_b, W_c1um_l, W_c1um_r, c1_um_bl, xm1_b, NM, NBLK_M,
        aggu, xu_b, W_c1mu_l, W_c1mu_r, c1_mu_bl, xu1_b, NU, 1);
    // conv2
    agg_bf16<<<AGG_BLOCKS, 256, 0, stream>>>(xu1_b, es_m, rp_m, aggm, NM,
                                             xm1_b, es_u, rp_u, aggu, NU);
    sage_mfma<<<NBLK_M + NBLK_U, 256, 0, stream>>>(
        aggm, xm1_b, W_c2um_l, W_c2um_r, c2_um_bl, zm, NM, NBLK_M,
        aggu, xu1_b, W_c2mu_l, W_c2mu_r, c2_mu_bl, zu, NU, 0);

    // decoder (bf16 MFMA, 3-phase, swapped operands -> vectorized epilogues)
    decoder_mfma<<<(NL + 63) / 64, 512, 0, stream>>>(
        zu, zm, eli, w1p, dec_b1, w2p, dec_b2, dec_W3, dec_b3, (float*)d_out);
}

// Round 12
// 1266.705 us; speedup vs baseline: 1.1253x; 1.0186x over previous
//
#include <hip/hip_runtime.h>

#define NU 100000
#define NM 20000
#define NE 2000000
#define NL 500000
#define H  128
#define MROW 48   // decoder rows/block: 72 KB LDS -> 2 blocks/CU (vs 96 KB/1 at M=64)

typedef __attribute__((ext_vector_type(8))) short bf16x8;            // 8 bf16 (4 VGPRs)
typedef __attribute__((ext_vector_type(4))) float floatx4;           // 4 fp32 acc
typedef __attribute__((ext_vector_type(8))) unsigned short u16x8;    // 16B load/store
typedef __attribute__((ext_vector_type(4))) unsigned short u16x4;    // 8B store

__device__ __forceinline__ unsigned short f2b(float x) {
    union { float f; unsigned u; } v; v.f = x;
    unsigned r = v.u + 0x7FFFu + ((v.u >> 16) & 1u);  // RNE
    return (unsigned short)(r >> 16);
}
__device__ __forceinline__ float b2f(unsigned short h) {
    union { unsigned u; float f; } v; v.u = ((unsigned)h) << 16;
    return v.f;
}
__device__ __forceinline__ float b2f_lo(unsigned v) {  // low ushort of packed pair
    union { unsigned u; float f; } t; t.u = v << 16; return t.f;
}
__device__ __forceinline__ float b2f_hi(unsigned v) {
    union { unsigned u; float f; } t; t.u = v & 0xFFFF0000u; return t.f;
}

// rotated LDS chunk addressing (chunk = 16B = 8 bf16), zero-waste bank pad.
#define SFCH(r, c)  ((r) * 32 + (((c) + (r)) & 31))   // rows x 32 chunks (256 cols)
#define SH1CH(r, c) ((r) * 16 + (((c) + (r)) & 15))   // rows x 16 chunks (128 cols)
#define SH2CH(r, c) ((r) * 64 + (((c) + (r)) & 63))   // rows x 64 chunks (512 cols)

// ---------------------------------------------------------------- transpose (proj weights only)
struct TDesc { const float* s; float* d; int R; int C; };
struct TPack { TDesc t[2]; };

__global__ __launch_bounds__(256) void transpose_all(TPack p) {
    TDesc d = p.t[blockIdx.y];
    int n = d.R * d.C;
    for (int i = blockIdx.x * 256 + threadIdx.x; i < n; i += gridDim.x * 256) {
        int r = i / d.C, c = i - r * d.C;
        d.d[c * d.R + r] = d.s[i];  // dst[k][h] = src[h][k]
    }
}

// ---------------------------------------------------------------- pack decoder weights into MFMA frag order
// (A-fragment and B-fragment lane layouts are identical for 16x16x32)
__global__ __launch_bounds__(256) void pack_weights(const float* __restrict__ W1,
                                                    const float* __restrict__ W2,
                                                    unsigned short* __restrict__ W1p,
                                                    unsigned short* __restrict__ W2p) {
    const int n = 512 * 256;
    for (int i = blockIdx.x * 256 + threadIdx.x; i < n; i += gridDim.x * 256) {
        int j = i & 7, lane = (i >> 3) & 63;
        int ln = lane & 15, lq = lane >> 4;
        int kg1 = (i >> 9) & 7,  t1 = i >> 12;
        W1p[i] = f2b(W1[(t1 * 16 + ln) * 256 + kg1 * 32 + lq * 8 + j]);
        int kg2 = (i >> 9) & 15, t2 = i >> 13;
        W2p[i] = f2b(W2[(t2 * 16 + ln) * 512 + kg2 * 32 + lq * 8 + j]);
    }
}

// ---------------------------------------------------------------- pack 8 sage weights (H x H) into B-frag order
struct SPack { const float* w[8]; };
__global__ __launch_bounds__(256) void pack_sage(SPack sp, unsigned short* __restrict__ out) {
    const int n = 8 * 16384;
    for (int i = blockIdx.x * 256 + threadIdx.x; i < n; i += gridDim.x * 256) {
        int j = i & 7, lane = (i >> 3) & 63;
        int kg = (i >> 9) & 3, t = (i >> 11) & 7, wsel = i >> 14;
        int ln = lane & 15, lq = lane >> 4;
        out[i] = f2b(sp.w[wsel][(t * 16 + ln) * H + kg * 32 + lq * 8 + j]);
    }
}

// ---------------------------------------------------------------- CSR build
__global__ __launch_bounds__(256) void deg_kernel(const int* __restrict__ ei,
                                                  int* rp_m, int* rp_u) {
    for (int i = blockIdx.x * 256 + threadIdx.x; i < NE; i += gridDim.x * 256) {
        int u = ei[i], m = ei[NE + i];
        atomicAdd(&rp_u[u + 1], 1);
        atomicAdd(&rp_m[m + 1], 1);
    }
}

__global__ __launch_bounds__(256) void scan2_kernel(int* rp_m, int n_m,
                                                    int* rp_u, int n_u) {
    int* a = (blockIdx.x == 0) ? rp_m : rp_u;
    int n  = (blockIdx.x == 0) ? n_m : n_u;
    __shared__ int s[256];
    __shared__ int carry;
    int tid = threadIdx.x;
    if (tid == 0) carry = 0;
    __syncthreads();
    for (int base = 0; base < n; base += 4096) {
        int v[16];
        int run = 0;
        int i0 = base + tid * 16;
#pragma unroll
        for (int i = 0; i < 16; ++i) {
            int x = (i0 + i < n) ? a[i0 + i] : 0;
            run += x; v[i] = run;
        }
        s[tid] = run;
        __syncthreads();
        for (int off = 1; off < 256; off <<= 1) {
            int t = (tid >= off) ? s[tid - off] : 0;
            __syncthreads();
            s[tid] += t;
            __syncthreads();
        }
        int prev = carry + (tid > 0 ? s[tid - 1] : 0);
#pragma unroll
        for (int i = 0; i < 16; ++i)
            if (i0 + i < n) a[i0 + i] = v[i] + prev;
        int total = s[255];
        __syncthreads();
        if (tid == 0) carry += total;
        __syncthreads();
    }
}

__global__ __launch_bounds__(256) void bucket_kernel(const int* __restrict__ ei,
        const int* __restrict__ rp_m, const int* __restrict__ rp_u,
        int* cur_m, int* cur_u, int* es_m, int* es_u) {
    for (int i = blockIdx.x * 256 + threadIdx.x; i < NE; i += gridDim.x * 256) {
        int u = ei[i], m = ei[NE + i];
        int pm = atomicAdd(&cur_m[m], 1);
        es_m[rp_m[m] + pm] = u;
        int pu = atomicAdd(&cur_u[u], 1);
        es_u[rp_u[u] + pu] = m;
    }
}

// ---------------------------------------------------------------- projection (Linear + BN(eval) + ReLU) -> bf16
template <int K>
__global__ __launch_bounds__(256, 2) void proj_kernel(
        const float* __restrict__ x, const float* __restrict__ Wt,
        const float* __restrict__ lb, const float* __restrict__ g,
        const float* __restrict__ bb, const float* __restrict__ bm,
        const float* __restrict__ bv, unsigned short* __restrict__ out, int N) {
    __shared__ float sA[64 * K];
    const int tid = threadIdx.x;
    const int row0 = blockIdx.x * 64;
    constexpr int F4 = K / 4;
#pragma unroll
    for (int i = 0; i < (64 * F4) / 256; ++i) {
        int idx = tid + i * 256;
        int r = idx / F4, c = idx - r * F4;
        int gr = min(row0 + r, N - 1);
        ((float4*)sA)[idx] = ((const float4*)(x + (size_t)gr * K))[c];
    }
    __syncthreads();
    const int h_t = tid & 31, r_t = tid >> 5;
    float acc[8][4] = {};
#pragma unroll 4
    for (int k = 0; k < K; k += 4) {
        float4 w[4];
#pragma unroll
        for (int kk = 0; kk < 4; ++kk)
            w[kk] = *(const float4*)(Wt + (k + kk) * H + h_t * 4);
#pragma unroll
        for (int rr = 0; rr < 8; ++rr) {
            float4 a = *(const float4*)(sA + (r_t * 8 + rr) * K + k);
            acc[rr][0] += a.x * w[0].x + a.y * w[1].x + a.z * w[2].x + a.w * w[3].x;
            acc[rr][1] += a.x * w[0].y + a.y * w[1].y + a.z * w[2].y + a.w * w[3].y;
            acc[rr][2] += a.x * w[0].z + a.y * w[1].z + a.z * w[2].z + a.w * w[3].z;
            acc[rr][3] += a.x * w[0].w + a.y * w[1].w + a.z * w[2].w + a.w * w[3].w;
        }
    }
    const int h = h_t * 4;
    float4 lb4 = *(const float4*)(lb + h);
    float4 g4  = *(const float4*)(g  + h);
    float4 bb4 = *(const float4*)(bb + h);
    float4 m4  = *(const float4*)(bm + h);
    float4 v4  = *(const float4*)(bv + h);
    float sc[4] = { g4.x * rsqrtf(v4.x + 1e-5f), g4.y * rsqrtf(v4.y + 1e-5f),
                    g4.z * rsqrtf(v4.z + 1e-5f), g4.w * rsqrtf(v4.w + 1e-5f) };
    float lbv[4] = { lb4.x, lb4.y, lb4.z, lb4.w };
    float mv[4]  = { m4.x, m4.y, m4.z, m4.w };
    float bbv[4] = { bb4.x, bb4.y, bb4.z, bb4.w };
#pragma unroll
    for (int rr = 0; rr < 8; ++rr) {
        int gr = row0 + r_t * 8 + rr;
        if (gr < N) {
            u16x4 o;
#pragma unroll
            for (int c = 0; c < 4; ++c)
                o[c] = f2b(fmaxf((acc[rr][c] + lbv[c] - mv[c]) * sc[c] + bbv[c], 0.0f));
            *(u16x4*)(out + (size_t)gr * H + h) = o;
        }
    }
}

// ---------------------------------------------------------------- segment mean (bf16 in/out, fp32 acc)
// one WAVE per node; 8 row-loads in flight (latency-bound gather).
__global__ __launch_bounds__(256) void agg_bf16(
        const unsigned short* __restrict__ srcA, const int* __restrict__ esA,
        const int* __restrict__ rpA, unsigned short* __restrict__ outA, int nA,
        const unsigned short* __restrict__ srcB, const int* __restrict__ esB,
        const int* __restrict__ rpB, unsigned short* __restrict__ outB, int nB) {
    int wid = blockIdx.x * 4 + (threadIdx.x >> 6);
    const int lane = threadIdx.x & 63;
    const unsigned short* src; const int* es; const int* rp; unsigned short* out; int n;
    if (wid < nA) { src = srcA; es = esA; rp = rpA; out = outA; n = wid; }
    else {
        wid -= nA;
        if (wid >= nB) return;
        src = srcB; es = esB; rp = rpB; out = outB; n = wid;
    }
    const int start = rp[n], end = rp[n + 1];
    float a0 = 0.0f, a1 = 0.0f;
    int j = start;
    for (; j + 8 <= end; j += 8) {
        unsigned v[8];
#pragma unroll
        for (int q = 0; q < 8; ++q)
            v[q] = *(const unsigned*)(src + (size_t)es[j + q] * H + lane * 2);
#pragma unroll
        for (int q = 0; q < 8; ++q) { a0 += b2f_lo(v[q]); a1 += b2f_hi(v[q]); }
    }
    for (; j < end; ++j) {
        unsigned v = *(const unsigned*)(src + (size_t)es[j] * H + lane * 2);
        a0 += b2f_lo(v); a1 += b2f_hi(v);
    }
    float inv = (end > start) ? 1.0f / (float)(end - start) : 0.0f;
    unsigned o = (unsigned)f2b(a0 * inv) | ((unsigned)f2b(a1 * inv) << 16);
    *(unsigned*)(out + (size_t)n * H + lane * 2) = o;
}

// ---------------------------------------------------------------- SAGE via MFMA
__global__ __launch_bounds__(256, 4) void sage_mfma(
        const unsigned short* __restrict__ aggA, const unsigned short* __restrict__ xA,
        const unsigned short* __restrict__ WlA, const unsigned short* __restrict__ WrA,
        const float* __restrict__ blA, unsigned short* __restrict__ outA, int NA, int NBLKA,
        const unsigned short* __restrict__ aggB, const unsigned short* __restrict__ xB,
        const unsigned short* __restrict__ WlB, const unsigned short* __restrict__ WrB,
        const float* __restrict__ blB, unsigned short* __restrict__ outB, int NB,
        int relu) {
    __shared__ unsigned short sAg[64 * 16 * 8];  // 16 KB
    __shared__ unsigned short sX[64 * 16 * 8];   // 16 KB
    const int tid = threadIdx.x;
    const unsigned short *agg, *x, *Wl, *Wr; const float* bl; unsigned short* out;
    int N, row0;
    if ((int)blockIdx.x < NBLKA) {
        agg = aggA; x = xA; Wl = WlA; Wr = WrA; bl = blA; out = outA; N = NA;
        row0 = blockIdx.x * 64;
    } else {
        agg = aggB; x = xB; Wl = WlB; Wr = WrB; bl = blB; out = outB; N = NB;
        row0 = (blockIdx.x - NBLKA) * 64;
    }
#pragma unroll
    for (int i = 0; i < 4; ++i) {
        int idx = tid + i * 256;           // 1024 chunks
        int r = idx >> 4, c = idx & 15;
        int gr = min(row0 + r, N - 1);
        *(u16x8*)(sAg + SH1CH(r, c) * 8) = *(const u16x8*)(agg + (size_t)gr * H + c * 8);
        *(u16x8*)(sX  + SH1CH(r, c) * 8) = *(const u16x8*)(x   + (size_t)gr * H + c * 8);
    }
    __syncthreads();
    const int lane = tid & 63, w = tid >> 6;
    const int ln = lane & 15, lq = lane >> 4;
    floatx4 acc[2][4] = {};
#pragma unroll 2
    for (int kg = 0; kg < 4; ++kg) {
        bf16x8 aA[4], aX[4];
#pragma unroll
        for (int mt = 0; mt < 4; ++mt) {
            aA[mt] = *(const bf16x8*)(sAg + SH1CH(mt * 16 + ln, kg * 4 + lq) * 8);
            aX[mt] = *(const bf16x8*)(sX  + SH1CH(mt * 16 + ln, kg * 4 + lq) * 8);
        }
#pragma unroll
        for (int nt = 0; nt < 2; ++nt) {
            int widx = ((w * 2 + nt) * 4 + kg) * 512 + lane * 8;
            bf16x8 bL = *(const bf16x8*)(Wl + widx);
            bf16x8 bR = *(const bf16x8*)(Wr + widx);
#pragma unroll
            for (int mt = 0; mt < 4; ++mt) {
                acc[nt][mt] = __builtin_amdgcn_mfma_f32_16x16x32_bf16(aA[mt], bL, acc[nt][mt], 0, 0, 0);
                acc[nt][mt] = __builtin_amdgcn_mfma_f32_16x16x32_bf16(aX[mt], bR, acc[nt][mt], 0, 0, 0);
            }
        }
    }
    __syncthreads();   // done reading sAg; reuse it for output staging
    {
#pragma unroll
        for (int nt = 0; nt < 2; ++nt) {
            int ncol = w * 32 + nt * 16 + ln;   // 0..127
            float bv = bl[ncol];
            int cch = ncol >> 3, coff = ncol & 7;
#pragma unroll
            for (int mt = 0; mt < 4; ++mt)
#pragma unroll
                for (int i = 0; i < 4; ++i) {
                    int row = mt * 16 + lq * 4 + i;
                    float v = acc[nt][mt][i] + bv;
                    if (relu) v = fmaxf(v, 0.0f);
                    sAg[SH1CH(row, cch) * 8 + coff] = f2b(v);
                }
        }
    }
    __syncthreads();
#pragma unroll
    for (int i = 0; i < 4; ++i) {
        int idx = tid + i * 256;
        int r = idx >> 4, c = idx & 15;
        int gr = row0 + r;
        if (gr < N)
            *(u16x8*)(out + (size_t)gr * H + c * 8) = *(const u16x8*)(sAg + SH1CH(r, c) * 8);
    }
}

// ---------------------------------------------------------------- fused edge decoder MLP — 3-phase, swapped operands, M=48
// M=48 rows/block: LDS = sF 24 KB + sH1 48 KB = 72 KB -> 2 blocks/CU (16
// waves/CU, 4/SIMD) vs M=64's 96 KB/1 block (R11: OccupancyPercent 22,
// MfmaUtil 33 — latency-bound at 2 waves/SIMD). Register plan at (512,4)
// = 128/wave: phase-1 peak acc1[4][3]=48 AGPR + ~56 in-flight + ptrs ~= 119.
__global__ __launch_bounds__(512, 4) void decoder_mfma(
        const unsigned short* __restrict__ zu, const unsigned short* __restrict__ zm,
        const int* __restrict__ eli,
        const unsigned short* __restrict__ W1p, const float* __restrict__ b1,
        const unsigned short* __restrict__ W2p, const float* __restrict__ b2,
        const float* __restrict__ W3, const float* __restrict__ b3,
        float* __restrict__ out) {
    __shared__ unsigned short sF[MROW * 32 * 8];   // feat MROWx256 bf16 rotated (24 KB), later h2
    __shared__ unsigned short sH1[MROW * 64 * 8];  // h1 FULL MROWx512 bf16 rotated (48 KB)
    const int tid = threadIdx.x;
    const int row0 = blockIdx.x * MROW;
    // ---- gather feat = [zu[eu] | zm[em]] (bf16 straight copy)
    {
        int r = tid >> 3, p = tid & 7;
        if (r < MROW) {
            int rg = min(row0 + r, NL - 1);
            int iu = eli[rg], im = eli[NL + rg];
            const unsigned short* zur = zu + (size_t)iu * H;
            const unsigned short* zmr = zm + (size_t)im * H;
#pragma unroll
            for (int j = 0; j < 4; ++j) {
                int c = p + j * 8;   // 0..31
                const unsigned short* s = (c < 16) ? (zur + c * 8) : (zmr + (c - 16) * 8);
                *(u16x8*)(sF + SFCH(r, c) * 8) = *(const u16x8*)s;
            }
        }
    }
    __syncthreads();
    const int lane = tid & 63, w = tid >> 6;   // 8 waves
    const int ln = lane & 15, lq = lane >> 4;
    // ---- phase 1: h1^T = W1 · feat^T ; wave w owns h1 cols [w*64, +64)
    {
        floatx4 acc1[4][3] = {};   // [nt: h1col tile][mt: edge-row tile]
        const unsigned short* w1base = W1p + ((size_t)(w * 4) * 8) * 512 + lane * 8;
#pragma unroll 2
        for (int kg = 0; kg < 8; ++kg) {
            bf16x8 fb[3];   // feat fragments (B operand): B[n=edge row][k]
#pragma unroll
            for (int mt = 0; mt < 3; ++mt)
                fb[mt] = *(const bf16x8*)(sF + SFCH(mt * 16 + ln, kg * 4 + lq) * 8);
#pragma unroll
            for (int nt = 0; nt < 4; ++nt) {
                bf16x8 wa = *(const bf16x8*)(w1base + (size_t)(nt * 8 + kg) * 512);  // A: W1 rows
#pragma unroll
                for (int mt = 0; mt < 3; ++mt)
                    acc1[nt][mt] = __builtin_amdgcn_mfma_f32_16x16x32_bf16(wa, fb[mt], acc1[nt][mt], 0, 0, 0);
            }
        }
        // epilogue: D[row=h1col lq*4+i][col=edge row ln] -> b64 store per (nt,mt)
#pragma unroll
        for (int nt = 0; nt < 4; ++nt) {
            int colbase = w * 64 + nt * 16 + lq * 4;   // h1 col of reg 0
            float4 bv = *(const float4*)(b1 + colbase);
            int cch = colbase >> 3, coff = colbase & 7;   // coff = (lq&1)*4
#pragma unroll
            for (int mt = 0; mt < 3; ++mt) {
                int erow = mt * 16 + ln;
                u16x4 o = { f2b(fmaxf(acc1[nt][mt][0] + bv.x, 0.0f)),
                            f2b(fmaxf(acc1[nt][mt][1] + bv.y, 0.0f)),
                            f2b(fmaxf(acc1[nt][mt][2] + bv.z, 0.0f)),
                            f2b(fmaxf(acc1[nt][mt][3] + bv.w, 0.0f)) };
                *(u16x4*)(sH1 + SH2CH(erow, cch) * 8 + coff) = o;
            }
        }
    }
    __syncthreads();
    // ---- phase 2: h2^T = W2 · h1^T over full K=512; wave w owns h2 cols [w*32,+32)
    floatx4 acc3[2][3] = {};
    {
        const unsigned short* w2base = W2p + ((size_t)(w * 2) * 16) * 512 + lane * 8;
#pragma unroll 2
        for (int kg = 0; kg < 16; ++kg) {
            bf16x8 hb[3];   // h1 fragments (B operand)
#pragma unroll
            for (int mt = 0; mt < 3; ++mt)
                hb[mt] = *(const bf16x8*)(sH1 + SH2CH(mt * 16 + ln, kg * 4 + lq) * 8);
#pragma unroll
            for (int nt = 0; nt < 2; ++nt) {
                bf16x8 wa = *(const bf16x8*)(w2base + (size_t)(nt * 16 + kg) * 512);
#pragma unroll
                for (int mt = 0; mt < 3; ++mt)
                    acc3[nt][mt] = __builtin_amdgcn_mfma_f32_16x16x32_bf16(wa, hb[mt], acc3[nt][mt], 0, 0, 0);
            }
        }
    }
    // ---- h2 = ReLU(acc3 + b2) -> sF overlay, b64 stores
    {
#pragma unroll
        for (int nt = 0; nt < 2; ++nt) {
            int colbase = w * 32 + nt * 16 + lq * 4;   // h2 col of reg 0
            float4 bv = *(const float4*)(b2 + colbase);
            int cch = colbase >> 3, coff = colbase & 7;
#pragma unroll
            for (int mt = 0; mt < 3; ++mt) {
                int erow = mt * 16 + ln;
                u16x4 o = { f2b(fmaxf(acc3[nt][mt][0] + bv.x, 0.0f)),
                            f2b(fmaxf(acc3[nt][mt][1] + bv.y, 0.0f)),
                            f2b(fmaxf(acc3[nt][mt][2] + bv.z, 0.0f)),
                            f2b(fmaxf(acc3[nt][mt][3] + bv.w, 0.0f)) };
                *(u16x4*)(sF + SFCH(erow, cch) * 8 + coff) = o;
            }
        }
    }
    __syncthreads();
    // ---- layer 3: out = h2 @ W3^T + b3
    {
        int r = tid >> 3, p = tid & 7;   // MROW rows x 8 threads (32 cols each)
        if (r < MROW) {
            float sum = 0.0f;
#pragma unroll
            for (int j = 0; j < 4; ++j) {
                int c = p + j * 8;
                const unsigned short* hp = sF + SFCH(r, c) * 8;
                const float* w3p = W3 + c * 8;
#pragma unroll
                for (int e = 0; e < 8; ++e) sum += b2f(hp[e]) * w3p[e];
            }
            sum += __shfl_down(sum, 4, 8);
            sum += __shfl_down(sum, 2, 8);
            sum += __shfl_down(sum, 1, 8);
            if (p == 0 && row0 + r < NL) out[row0 + r] = sum + b3[0];
        }
    }
}

// ---------------------------------------------------------------- host
extern "C" void kernel_launch(void* const* d_in, const int* in_sizes, int n_in,
                              void* d_out, int out_size, void* d_ws, size_t ws_size,
                              hipStream_t stream) {
    const float* x_user  = (const float*)d_in[0];
    const float* x_movie = (const float*)d_in[1];
    const int*   ei      = (const int*)d_in[2];
    const int*   eli     = (const int*)d_in[3];
    const float* lin_u_W = (const float*)d_in[4];
    const float* lin_u_b = (const float*)d_in[5];
    const float* lin_m_W = (const float*)d_in[6];
    const float* lin_m_b = (const float*)d_in[7];
    const float* bn_u_g  = (const float*)d_in[8];
    const float* bn_u_b  = (const float*)d_in[9];
    const float* bn_u_m  = (const float*)d_in[10];
    const float* bn_u_v  = (const float*)d_in[11];
    const float* bn_m_g  = (const float*)d_in[12];
    const float* bn_m_b  = (const float*)d_in[13];
    const float* bn_m_m  = (const float*)d_in[14];
    const float* bn_m_v  = (const float*)d_in[15];
    const float* c1_um_Wl = (const float*)d_in[16];
    const float* c1_um_bl = (const float*)d_in[17];
    const float* c1_um_Wr = (const float*)d_in[18];
    const float* c1_mu_Wl = (const float*)d_in[19];
    const float* c1_mu_bl = (const float*)d_in[20];
    const float* c1_mu_Wr = (const float*)d_in[21];
    const float* c2_um_Wl = (const float*)d_in[22];
    const float* c2_um_bl = (const float*)d_in[23];
    const float* c2_um_Wr = (const float*)d_in[24];
    const float* c2_mu_Wl = (const float*)d_in[25];
    const float* c2_mu_bl = (const float*)d_in[26];
    const float* c2_mu_Wr = (const float*)d_in[27];
    const float* dec_W1 = (const float*)d_in[28];
    const float* dec_b1 = (const float*)d_in[29];
    const float* dec_W2 = (const float*)d_in[30];
    const float* dec_b2 = (const float*)d_in[31];
    const float* dec_W3 = (const float*)d_in[32];
    const float* dec_b3 = (const float*)d_in[33];

    char* base = (char*)d_ws;
    size_t off = 0;
    auto alloc = [&](size_t bytes) -> char* {
        char* p = base + off;
        off += (bytes + 255) & ~(size_t)255;
        return p;
    };
    unsigned short* xu_b  = (unsigned short*)alloc((size_t)NU * H * 2);
    unsigned short* xm_b  = (unsigned short*)alloc((size_t)NM * H * 2);
    unsigned short* xu1_b = (unsigned short*)alloc((size_t)NU * H * 2);
    unsigned short* xm1_b = (unsigned short*)alloc((size_t)NM * H * 2);
    unsigned short* aggu  = (unsigned short*)alloc((size_t)NU * H * 2);
    unsigned short* aggm  = (unsigned short*)alloc((size_t)NM * H * 2);
    float* wt_u = (float*)alloc((size_t)64 * H * 4);
    float* wt_m = (float*)alloc((size_t)H * H * 4);
    unsigned short* wsg = (unsigned short*)alloc((size_t)8 * 16384 * 2);  // packed sage weights
    unsigned short* w1p = (unsigned short*)alloc((size_t)512 * 256 * 2);
    unsigned short* w2p = (unsigned short*)alloc((size_t)256 * 512 * 2);
    int* rp_m  = (int*)alloc((size_t)(NM + 1) * 4);
    int* rp_u  = (int*)alloc((size_t)(NU + 1) * 4);
    int* cur_m = (int*)alloc((size_t)NM * 4);
    int* cur_u = (int*)alloc((size_t)NU * 4);
    int* es_m  = (int*)alloc((size_t)NE * 4);
    int* es_u  = (int*)alloc((size_t)NE * 4);
    unsigned short* zu = xu_b;   // xu_b dead after conv1 sage -> reuse
    unsigned short* zm = xm_b;

    // zero CSR meta (rp_m .. cur_u incl. padding)
    hipMemsetAsync(rp_m, 0, (size_t)((char*)es_m - (char*)rp_m), stream);

    TPack tp;
    tp.t[0] = { lin_u_W, wt_u, H, 64 };
    tp.t[1] = { lin_m_W, wt_m, H, H };
    transpose_all<<<dim3(64, 2), 256, 0, stream>>>(tp);
    pack_weights<<<256, 256, 0, stream>>>(dec_W1, dec_W2, w1p, w2p);
    SPack sp;
    sp.w[0] = c1_um_Wl; sp.w[1] = c1_um_Wr; sp.w[2] = c1_mu_Wl; sp.w[3] = c1_mu_Wr;
    sp.w[4] = c2_um_Wl; sp.w[5] = c2_um_Wr; sp.w[6] = c2_mu_Wl; sp.w[7] = c2_mu_Wr;
    pack_sage<<<128, 256, 0, stream>>>(sp, wsg);
    const unsigned short* W_c1um_l = wsg + 0 * 16384;
    const unsigned short* W_c1um_r = wsg + 1 * 16384;
    const unsigned short* W_c1mu_l = wsg + 2 * 16384;
    const unsigned short* W_c1mu_r = wsg + 3 * 16384;
    const unsigned short* W_c2um_l = wsg + 4 * 16384;
    const unsigned short* W_c2um_r = wsg + 5 * 16384;
    const unsigned short* W_c2mu_l = wsg + 6 * 16384;
    const unsigned short* W_c2mu_r = wsg + 7 * 16384;

    deg_kernel<<<2048, 256, 0, stream>>>(ei, rp_m, rp_u);
    scan2_kernel<<<2, 256, 0, stream>>>(rp_m, NM + 1, rp_u, NU + 1);
    bucket_kernel<<<2048, 256, 0, stream>>>(ei, rp_m, rp_u, cur_m, cur_u, es_m, es_u);

    proj_kernel<64><<<(NU + 63) / 64, 256, 0, stream>>>(
        x_user, wt_u, lin_u_b, bn_u_g, bn_u_b, bn_u_m, bn_u_v, xu_b, NU);
    proj_kernel<128><<<(NM + 63) / 64, 256, 0, stream>>>(
        x_movie, wt_m, lin_m_b, bn_m_g, bn_m_b, bn_m_m, bn_m_v, xm_b, NM);

    const int AGG_BLOCKS = (NM + NU + 3) / 4;
    const int NBLK_M = (NM + 63) / 64, NBLK_U = (NU + 63) / 64;

    // conv1
    agg_bf16<<<AGG_BLOCKS, 256, 0, stream>>>(xu_b, es_m, rp_m, aggm, NM,
                                             xm_b, es_u, rp_u, aggu, NU);
    sage_mfma<<<NBLK_M + NBLK_U, 256, 0, stream>>>(
        aggm, xm_b, W_c1um_l, W_c1um_r, c1_um_bl, xm1_b, NM, NBLK_M,
        aggu, xu_b, W_c1mu_l, W_c1mu_r, c1_mu_bl, xu1_b, NU, 1);
    // conv2
    agg_bf16<<<AGG_BLOCKS, 256, 0, stream>>>(xu1_b, es_m, rp_m, aggm, NM,
                                             xm1_b, es_u, rp_u, aggu, NU);
    sage_mfma<<<NBLK_M + NBLK_U, 256, 0, stream>>>(
        aggm, xm1_b, W_c2um_l, W_c2um_r, c2_um_bl, zm, NM, NBLK_M,
        aggu, xu1_b, W_c2mu_l, W_c2mu_r, c2_mu_bl, zu, NU, 0);

    // decoder (bf16 MFMA, 3-phase, M=48, 72 KB LDS -> 2 blocks/CU)
    decoder_mfma<<<(NL + MROW - 1) / MROW, 512, 0, stream>>>(
        zu, zm, eli, w1p, dec_b1, w2p, dec_b2, dec_W3, dec_b3, (float*)d_out);
}